// Round 2
// baseline (574.213 us; speedup 1.0000x reference)
//
#include <hip/hip_runtime.h>
#include <stdint.h>

#define N_NODES 30000
#define N_EDGES 300000
#define D_IN    128
#define D_HID   256
#define D_OUTF  64
#define BN_EPS  1e-5f
#define NEG_SLOPE 0.2f

__device__ __forceinline__ float lrelu(float a) { return fmaxf(a, NEG_SLOPE * a); }

// ---------------- CSR build ----------------
__global__ void k_init_zero(int* cnt, float* stats) {
    int i = blockIdx.x * 256 + threadIdx.x;
    if (i < N_NODES) cnt[i] = 0;
    if (i < 1344) stats[i] = 0.f;
}

__global__ void k_count(const int* __restrict__ dst, int* __restrict__ cnt) {
    int e = blockIdx.x * 256 + threadIdx.x;
    if (e < N_EDGES) atomicAdd(&cnt[dst[e]], 1);
}

__global__ void k_scan1(const int* __restrict__ cnt, int* __restrict__ rowptr, int* __restrict__ bsums) {
    __shared__ int s[256];
    int tid = threadIdx.x;
    int idx = blockIdx.x * 256 + tid;
    int val = (idx < N_NODES) ? cnt[idx] : 0;
    s[tid] = val; __syncthreads();
    for (int o = 1; o < 256; o <<= 1) {
        int add = (tid >= o) ? s[tid - o] : 0;
        __syncthreads();
        s[tid] += add;
        __syncthreads();
    }
    if (idx < N_NODES) rowptr[idx] = s[tid] - val;  // exclusive (local)
    if (tid == 255) bsums[blockIdx.x] = s[255];
}

__global__ void k_scan2(int* bsums, int nb) {
    __shared__ int s[128];
    int tid = threadIdx.x;
    int val = (tid < nb) ? bsums[tid] : 0;
    s[tid] = val; __syncthreads();
    for (int o = 1; o < 128; o <<= 1) {
        int add = (tid >= o) ? s[tid - o] : 0;
        __syncthreads();
        s[tid] += add;
        __syncthreads();
    }
    if (tid < nb) bsums[tid] = s[tid] - val;  // exclusive
}

__global__ void k_scan3(int* __restrict__ rowptr, const int* __restrict__ bsums, int* __restrict__ cnt) {
    int idx = blockIdx.x * 256 + threadIdx.x;
    if (idx < N_NODES) { rowptr[idx] += bsums[idx >> 8]; cnt[idx] = 0; }
    if (idx == 0) rowptr[N_NODES] = N_EDGES;
}

__global__ void k_fill(const int* __restrict__ srcA, const int* __restrict__ dstA,
                       const int* __restrict__ rowptr, int* __restrict__ cnt, int* __restrict__ col) {
    int e = blockIdx.x * 256 + threadIdx.x;
    if (e < N_EDGES) {
        int d = dstA[e];
        int pos = rowptr[d] + atomicAdd(&cnt[d], 1);
        col[pos] = srcA[e];
    }
}

// ---------------- SAGE mean aggregation: one wave per node ----------------
template<int D>
__global__ void __launch_bounds__(256) k_sage_agg(const float* __restrict__ X,
                                                  const int* __restrict__ rowptr,
                                                  const int* __restrict__ col,
                                                  float* __restrict__ out) {
    constexpr int V = D / 64;
    int lane = threadIdx.x & 63;
    int i = (blockIdx.x << 2) + (threadIdx.x >> 6);
    if (i >= N_NODES) return;
    int b = rowptr[i], e = rowptr[i + 1];
    float acc[V] = {};
    for (int p = b; p < e; ++p) {
        int j = col[p];
        if constexpr (V == 2) {
            float2 v = *(const float2*)(X + (size_t)j * D + lane * 2);
            acc[0] += v.x; acc[1] += v.y;
        } else {
            float4 v = *(const float4*)(X + (size_t)j * D + lane * 4);
            acc[0] += v.x; acc[1] += v.y; acc[2] += v.z; acc[3] += v.w;
        }
    }
    float inv = 1.f / fmaxf((float)(e - b), 1.f);
    if constexpr (V == 2) {
        *(float2*)(out + (size_t)i * D + lane * 2) = make_float2(acc[0] * inv, acc[1] * inv);
    } else {
        *(float4*)(out + (size_t)i * D + lane * 4) =
            make_float4(acc[0] * inv, acc[1] * inv, acc[2] * inv, acc[3] * inv);
    }
}

// ---------------- dual GEMM: C = A1@B1 + A2@B2 + bias ----------------
// A: [M,K] row-major, B: [K,NN] row-major, C: [M,NN]
template<int TM, int TN>
__global__ void __launch_bounds__(256) k_gemm(const float* __restrict__ A1, const float* __restrict__ B1, int K1,
                                              const float* __restrict__ A2, const float* __restrict__ B2, int K2,
                                              const float* __restrict__ bias, float* __restrict__ C,
                                              int M, int NN) {
    constexpr int BM = TM * 16, BN = TN * 16, BK = 16;
    __shared__ float As[BK][BM + 4];
    __shared__ float Bs[BK][BN + 4];
    int tid = threadIdx.x;
    int ty = tid >> 4, tx = tid & 15;
    int mBase = blockIdx.x * BM, nBase = blockIdx.y * BN;
    float acc[TM][TN] = {};

    for (int pair = 0; pair < 2; ++pair) {
        const float* A = pair ? A2 : A1;
        const float* B = pair ? B2 : B1;
        int K = pair ? K2 : K1;
        if (K == 0) break;
        for (int k0 = 0; k0 < K; k0 += BK) {
            constexpr int AV = BM * BK / (256 * 4);
            #pragma unroll
            for (int v = 0; v < AV; ++v) {
                int l = tid + v * 256;
                int r = l >> 2;
                int c = (l & 3) << 2;
                int row = mBase + r;
                float4 val = (row < M) ? *(const float4*)&A[(size_t)row * K + k0 + c]
                                       : make_float4(0.f, 0.f, 0.f, 0.f);
                As[c + 0][r] = val.x; As[c + 1][r] = val.y;
                As[c + 2][r] = val.z; As[c + 3][r] = val.w;
            }
            constexpr int BV = BN * BK / (256 * 4);
            #pragma unroll
            for (int v = 0; v < BV; ++v) {
                int l = tid + v * 256;
                int r = l / (BN / 4);
                int c = (l % (BN / 4)) * 4;
                float4 val = *(const float4*)&B[(size_t)(k0 + r) * NN + nBase + c];
                *(float4*)&Bs[r][c] = val;
            }
            __syncthreads();
            #pragma unroll
            for (int kk = 0; kk < BK; ++kk) {
                float a[TM], b[TN];
                #pragma unroll
                for (int i = 0; i < TM; ++i) a[i] = As[kk][ty * TM + i];
                #pragma unroll
                for (int j = 0; j < TN; ++j) b[j] = Bs[kk][tx * TN + j];
                #pragma unroll
                for (int i = 0; i < TM; ++i)
                    #pragma unroll
                    for (int j = 0; j < TN; ++j)
                        acc[i][j] += a[i] * b[j];
            }
            __syncthreads();
        }
    }

    #pragma unroll
    for (int i = 0; i < TM; ++i) {
        int row = mBase + ty * TM + i;
        if (row >= M) continue;
        #pragma unroll
        for (int j = 0; j < TN; j += 4) {
            int colc = nBase + tx * TN + j;
            float4 o = make_float4(acc[i][j], acc[i][j + 1], acc[i][j + 2], acc[i][j + 3]);
            if (bias) {
                o.x += bias[colc]; o.y += bias[colc + 1];
                o.z += bias[colc + 2]; o.w += bias[colc + 3];
            }
            *(float4*)&C[(size_t)row * NN + colc] = o;
        }
    }
}

// ---------------- BatchNorm ----------------
template<int C>
__global__ void k_colstats(const float* __restrict__ X, float* __restrict__ sum, float* __restrict__ sq) {
    constexpr int RPB = 256 / C;
    int tid = threadIdx.x;
    int c = tid % C;
    int r0 = blockIdx.x * RPB + tid / C;
    float s = 0.f, q = 0.f;
    for (int r = r0; r < N_NODES; r += gridDim.x * RPB) {
        float v = X[(size_t)r * C + c];
        s += v; q += v * v;
    }
    atomicAdd(&sum[c], s);
    atomicAdd(&sq[c], q);
}

template<int C>
__global__ void k_finstats(const float* __restrict__ sum, const float* __restrict__ sq,
                           const float* __restrict__ g, const float* __restrict__ be,
                           float* __restrict__ A, float* __restrict__ B) {
    int c = threadIdx.x;
    if (c < C) {
        float mu = sum[c] * (1.f / N_NODES);
        float var = sq[c] * (1.f / N_NODES) - mu * mu;
        float a = g[c] * rsqrtf(var + BN_EPS);
        A[c] = a;
        B[c] = be[c] - a * mu;
    }
}

template<int C>
__global__ void k_bnrelu(float* __restrict__ X, const float* __restrict__ A, const float* __restrict__ B) {
    size_t total4 = (size_t)N_NODES * C / 4;
    for (size_t i = blockIdx.x * (size_t)blockDim.x + threadIdx.x; i < total4;
         i += (size_t)gridDim.x * blockDim.x) {
        int c4 = (int)((i * 4) % C);
        float4 x = ((float4*)X)[i];
        float4 a = *(const float4*)&A[c4];
        float4 b = *(const float4*)&B[c4];
        x.x = fmaxf(a.x * x.x + b.x, 0.f);
        x.y = fmaxf(a.y * x.y + b.y, 0.f);
        x.z = fmaxf(a.z * x.z + b.z, 0.f);
        x.w = fmaxf(a.w * x.w + b.w, 0.f);
        ((float4*)X)[i] = x;
    }
}

// ---------------- GAT attention coefficients ----------------
__global__ void __launch_bounds__(256) k_attn(const float* __restrict__ xp,
                                              const float* __restrict__ att_src,
                                              const float* __restrict__ att_dst,
                                              float* __restrict__ att) {
    int lane = threadIdx.x & 63;
    int i = (blockIdx.x << 2) + (threadIdx.x >> 6);
    if (i >= N_NODES) return;
    #pragma unroll
    for (int h = 0; h < 4; ++h) {
        float v = xp[(size_t)i * 256 + h * 64 + lane];
        float s = v * att_src[h * 64 + lane];
        float d = v * att_dst[h * 64 + lane];
        #pragma unroll
        for (int o = 32; o; o >>= 1) {
            s += __shfl_xor(s, o);
            d += __shfl_xor(d, o);
        }
        if (lane == 0) { att[i * 8 + h] = s; att[i * 8 + 4 + h] = d; }
    }
}

// ---------------- GAT softmax + aggregate + head-mean + relu + node-mean ----------------
__global__ void __launch_bounds__(256) k_gat(const float* __restrict__ xp,
                                             const float* __restrict__ att,
                                             const int* __restrict__ rowptr,
                                             const int* __restrict__ col,
                                             const float* __restrict__ bg,
                                             float* __restrict__ accout) {
    __shared__ float bsum[64];
    int tid = threadIdx.x;
    if (tid < 64) bsum[tid] = 0.f;
    __syncthreads();
    int lane = tid & 63;
    int gw = (blockIdx.x << 2) + (tid >> 6);
    int stride = gridDim.x << 2;
    float ysum = 0.f;
    float bgl = bg[lane];
    for (int i = gw; i < N_NODES; i += stride) {
        int b = rowptr[i], e = rowptr[i + 1];
        float4 ai = *(const float4*)(att + (size_t)i * 8);      // a_src[i]
        float4 ad = *(const float4*)(att + (size_t)i * 8 + 4);  // a_dst[i]
        float es[4], m[4];
        es[0] = lrelu(ai.x + ad.x); es[1] = lrelu(ai.y + ad.y);
        es[2] = lrelu(ai.z + ad.z); es[3] = lrelu(ai.w + ad.w);
        m[0] = es[0]; m[1] = es[1]; m[2] = es[2]; m[3] = es[3];
        for (int p = b; p < e; ++p) {
            int j = col[p];
            float4 aj = *(const float4*)(att + (size_t)j * 8);
            m[0] = fmaxf(m[0], lrelu(aj.x + ad.x));
            m[1] = fmaxf(m[1], lrelu(aj.y + ad.y));
            m[2] = fmaxf(m[2], lrelu(aj.z + ad.z));
            m[3] = fmaxf(m[3], lrelu(aj.w + ad.w));
        }
        const float* xpi = xp + (size_t)i * 256 + lane;
        float s[4], acc[4];
        #pragma unroll
        for (int h = 0; h < 4; ++h) {
            float w = __expf(es[h] - m[h]);
            s[h] = w;
            acc[h] = w * xpi[h * 64];
        }
        for (int p = b; p < e; ++p) {
            int j = col[p];
            float4 aj = *(const float4*)(att + (size_t)j * 8);
            const float* xpj = xp + (size_t)j * 256 + lane;
            float w0 = __expf(lrelu(aj.x + ad.x) - m[0]); s[0] += w0; acc[0] += w0 * xpj[0];
            float w1 = __expf(lrelu(aj.y + ad.y) - m[1]); s[1] += w1; acc[1] += w1 * xpj[64];
            float w2 = __expf(lrelu(aj.z + ad.z) - m[2]); s[2] += w2; acc[2] += w2 * xpj[128];
            float w3 = __expf(lrelu(aj.w + ad.w) - m[3]); s[3] += w3; acc[3] += w3 * xpj[192];
        }
        float y = 0.25f * (acc[0] / s[0] + acc[1] / s[1] + acc[2] / s[2] + acc[3] / s[3]) + bgl;
        ysum += fmaxf(y, 0.f);
    }
    atomicAdd(&bsum[lane], ysum);
    __syncthreads();
    if (tid < 64) atomicAdd(accout + tid, bsum[tid]);
}

__global__ void k_final(const float* __restrict__ accout, float* __restrict__ out) {
    int d = threadIdx.x;
    if (d < 64) out[d] = accout[d] * (1.f / N_NODES);
}

// ---------------- launch ----------------
extern "C" void kernel_launch(void* const* d_in, const int* in_sizes, int n_in,
                              void* d_out, int out_size, void* d_ws, size_t ws_size,
                              hipStream_t stream) {
    const float* x       = (const float*)d_in[0];
    const int*   ei      = (const int*)d_in[1];
    const float* W1l     = (const float*)d_in[2];
    const float* b1l     = (const float*)d_in[3];
    const float* W1r     = (const float*)d_in[4];
    const float* W2l     = (const float*)d_in[5];
    const float* b2l     = (const float*)d_in[6];
    const float* W2r     = (const float*)d_in[7];
    const float* g1      = (const float*)d_in[8];
    const float* be1     = (const float*)d_in[9];
    const float* g2      = (const float*)d_in[10];
    const float* be2     = (const float*)d_in[11];
    const float* Wg      = (const float*)d_in[12];
    const float* att_src = (const float*)d_in[13];
    const float* att_dst = (const float*)d_in[14];
    const float* bg      = (const float*)d_in[15];
    float* out = (float*)d_out;

    char* p = (char*)d_ws;
    auto alloc = [&](size_t bytes) -> char* {
        char* q = p;
        p += (bytes + 255) & ~(size_t)255;
        return q;
    };
    int*   cnt    = (int*)alloc((size_t)N_NODES * 4);
    float* stats  = (float*)alloc(1344 * 4);
    int*   rowptr = (int*)alloc((size_t)(N_NODES + 1) * 4);
    int*   bsums  = (int*)alloc(256 * 4);
    int*   col    = (int*)alloc((size_t)N_EDGES * 4);
    float* agg1   = (float*)alloc((size_t)N_NODES * 128 * 4);
    float* h1     = (float*)alloc((size_t)N_NODES * 256 * 4);
    float* agg2   = (float*)alloc((size_t)N_NODES * 256 * 4);  // later reused as xp
    float* h2     = (float*)alloc((size_t)N_NODES * 64 * 4);
    float* att    = (float*)alloc((size_t)N_NODES * 8 * 4);

    float* sum1 = stats;        float* sq1 = stats + 256;
    float* A1s  = stats + 512;  float* B1s = stats + 768;
    float* sum2 = stats + 1024; float* sq2 = stats + 1088;
    float* A2s  = stats + 1152; float* B2s = stats + 1216;
    float* accout = stats + 1280;

    const int* srcA = ei;
    const int* dstA = ei + N_EDGES;

    // CSR build
    k_init_zero<<<118, 256, 0, stream>>>(cnt, stats);
    k_count<<<(N_EDGES + 255) / 256, 256, 0, stream>>>(dstA, cnt);
    k_scan1<<<118, 256, 0, stream>>>(cnt, rowptr, bsums);
    k_scan2<<<1, 128, 0, stream>>>(bsums, 118);
    k_scan3<<<118, 256, 0, stream>>>(rowptr, bsums, cnt);
    k_fill<<<(N_EDGES + 255) / 256, 256, 0, stream>>>(srcA, dstA, rowptr, cnt, col);

    // SAGE layer 1
    k_sage_agg<128><<<(N_NODES + 3) / 4, 256, 0, stream>>>(x, rowptr, col, agg1);
    k_gemm<8, 8><<<dim3(235, 2), 256, 0, stream>>>(agg1, W1l, 128, x, W1r, 128, b1l, h1, N_NODES, 256);
    k_colstats<256><<<120, 256, 0, stream>>>(h1, sum1, sq1);
    k_finstats<256><<<1, 256, 0, stream>>>(sum1, sq1, g1, be1, A1s, B1s);
    k_bnrelu<256><<<1024, 256, 0, stream>>>(h1, A1s, B1s);

    // SAGE layer 2
    k_sage_agg<256><<<(N_NODES + 3) / 4, 256, 0, stream>>>(h1, rowptr, col, agg2);
    k_gemm<8, 4><<<dim3(235, 1), 256, 0, stream>>>(agg2, W2l, 256, h1, W2r, 256, b2l, h2, N_NODES, 64);
    k_colstats<64><<<120, 256, 0, stream>>>(h2, sum2, sq2);
    k_finstats<64><<<1, 64, 0, stream>>>(sum2, sq2, g2, be2, A2s, B2s);
    k_bnrelu<64><<<512, 256, 0, stream>>>(h2, A2s, B2s);

    // GAT
    float* xp = agg2;  // agg2 is dead after gemm2; reuse as xp
    k_gemm<8, 8><<<dim3(235, 2), 256, 0, stream>>>(h2, Wg, 64, nullptr, nullptr, 0, nullptr, xp, N_NODES, 256);
    k_attn<<<(N_NODES + 3) / 4, 256, 0, stream>>>(xp, att_src, att_dst, att);
    k_gat<<<512, 256, 0, stream>>>(xp, att, rowptr, col, bg, accout);
    k_final<<<1, 64, 0, stream>>>(accout, out);
}

// Round 3
// 491.229 us; speedup vs baseline: 1.1689x; 1.1689x over previous
//
#include <hip/hip_runtime.h>
#include <stdint.h>

#define N_NODES 30000
#define N_EDGES 300000
#define D_IN    128
#define D_HID   256
#define D_OUTF  64
#define BN_EPS  1e-5f
#define NEG_SLOPE 0.2f

__device__ __forceinline__ float lrelu(float a) { return fmaxf(a, NEG_SLOPE * a); }

// ---------------- CSR build ----------------
__global__ void k_init_zero(int* cnt, float* stats) {
    int i = blockIdx.x * 256 + threadIdx.x;
    if (i < N_NODES) cnt[i] = 0;
    if (i < 1344) stats[i] = 0.f;
}

__global__ void k_count(const int* __restrict__ dst, int* __restrict__ cnt) {
    int e = blockIdx.x * 256 + threadIdx.x;
    if (e < N_EDGES) atomicAdd(&cnt[dst[e]], 1);
}

__global__ void k_scan1(const int* __restrict__ cnt, int* __restrict__ rowptr, int* __restrict__ bsums) {
    __shared__ int s[256];
    int tid = threadIdx.x;
    int idx = blockIdx.x * 256 + tid;
    int val = (idx < N_NODES) ? cnt[idx] : 0;
    s[tid] = val; __syncthreads();
    for (int o = 1; o < 256; o <<= 1) {
        int add = (tid >= o) ? s[tid - o] : 0;
        __syncthreads();
        s[tid] += add;
        __syncthreads();
    }
    if (idx < N_NODES) rowptr[idx] = s[tid] - val;  // exclusive (local)
    if (tid == 255) bsums[blockIdx.x] = s[255];
}

__global__ void k_scan2(int* bsums, int nb) {
    __shared__ int s[128];
    int tid = threadIdx.x;
    int val = (tid < nb) ? bsums[tid] : 0;
    s[tid] = val; __syncthreads();
    for (int o = 1; o < 128; o <<= 1) {
        int add = (tid >= o) ? s[tid - o] : 0;
        __syncthreads();
        s[tid] += add;
        __syncthreads();
    }
    if (tid < nb) bsums[tid] = s[tid] - val;  // exclusive
}

__global__ void k_scan3(int* __restrict__ rowptr, const int* __restrict__ bsums, int* __restrict__ cnt) {
    int idx = blockIdx.x * 256 + threadIdx.x;
    if (idx < N_NODES) { rowptr[idx] += bsums[idx >> 8]; cnt[idx] = 0; }
    if (idx == 0) rowptr[N_NODES] = N_EDGES;
}

__global__ void k_fill(const int* __restrict__ srcA, const int* __restrict__ dstA,
                       const int* __restrict__ rowptr, int* __restrict__ cnt, int* __restrict__ col) {
    int e = blockIdx.x * 256 + threadIdx.x;
    if (e < N_EDGES) {
        int d = dstA[e];
        int pos = rowptr[d] + atomicAdd(&cnt[d], 1);
        col[pos] = srcA[e];
    }
}

// ---------------- SAGE mean aggregation: one wave per node ----------------
template<int D>
__global__ void __launch_bounds__(256) k_sage_agg(const float* __restrict__ X,
                                                  const int* __restrict__ rowptr,
                                                  const int* __restrict__ col,
                                                  float* __restrict__ out) {
    constexpr int V = D / 64;
    int lane = threadIdx.x & 63;
    int i = (blockIdx.x << 2) + (threadIdx.x >> 6);
    if (i >= N_NODES) return;
    int b = rowptr[i], e = rowptr[i + 1];
    float acc[V] = {};
    for (int p = b; p < e; ++p) {
        int j = col[p];
        if constexpr (V == 2) {
            float2 v = *(const float2*)(X + (size_t)j * D + lane * 2);
            acc[0] += v.x; acc[1] += v.y;
        } else {
            float4 v = *(const float4*)(X + (size_t)j * D + lane * 4);
            acc[0] += v.x; acc[1] += v.y; acc[2] += v.z; acc[3] += v.w;
        }
    }
    float inv = 1.f / fmaxf((float)(e - b), 1.f);
    if constexpr (V == 2) {
        *(float2*)(out + (size_t)i * D + lane * 2) = make_float2(acc[0] * inv, acc[1] * inv);
    } else {
        *(float4*)(out + (size_t)i * D + lane * 4) =
            make_float4(acc[0] * inv, acc[1] * inv, acc[2] * inv, acc[3] * inv);
    }
}

// ---------------- dual GEMM: C = A1@B1 + A2@B2 + bias ----------------
// A: [M,K] row-major, B: [K,NN] row-major, C: [M,NN]
template<int TM, int TN>
__global__ void __launch_bounds__(256) k_gemm(const float* __restrict__ A1, const float* __restrict__ B1, int K1,
                                              const float* __restrict__ A2, const float* __restrict__ B2, int K2,
                                              const float* __restrict__ bias, float* __restrict__ C,
                                              int M, int NN) {
    constexpr int BM = TM * 16, BN = TN * 16, BK = 16;
    __shared__ float As[BK][BM + 4];
    __shared__ float Bs[BK][BN + 4];
    int tid = threadIdx.x;
    int ty = tid >> 4, tx = tid & 15;
    int mBase = blockIdx.x * BM, nBase = blockIdx.y * BN;
    float acc[TM][TN] = {};

    for (int pair = 0; pair < 2; ++pair) {
        const float* A = pair ? A2 : A1;
        const float* B = pair ? B2 : B1;
        int K = pair ? K2 : K1;
        if (K == 0) break;
        for (int k0 = 0; k0 < K; k0 += BK) {
            constexpr int AV = BM * BK / (256 * 4);
            #pragma unroll
            for (int v = 0; v < AV; ++v) {
                int l = tid + v * 256;
                int r = l >> 2;
                int c = (l & 3) << 2;
                int row = mBase + r;
                float4 val = (row < M) ? *(const float4*)&A[(size_t)row * K + k0 + c]
                                       : make_float4(0.f, 0.f, 0.f, 0.f);
                As[c + 0][r] = val.x; As[c + 1][r] = val.y;
                As[c + 2][r] = val.z; As[c + 3][r] = val.w;
            }
            constexpr int BV = BN * BK / (256 * 4);
            #pragma unroll
            for (int v = 0; v < BV; ++v) {
                int l = tid + v * 256;
                int r = l / (BN / 4);
                int c = (l % (BN / 4)) * 4;
                float4 val = *(const float4*)&B[(size_t)(k0 + r) * NN + nBase + c];
                *(float4*)&Bs[r][c] = val;
            }
            __syncthreads();
            #pragma unroll
            for (int kk = 0; kk < BK; ++kk) {
                float a[TM], b[TN];
                #pragma unroll
                for (int i = 0; i < TM; ++i) a[i] = As[kk][ty * TM + i];
                #pragma unroll
                for (int j = 0; j < TN; ++j) b[j] = Bs[kk][tx * TN + j];
                #pragma unroll
                for (int i = 0; i < TM; ++i)
                    #pragma unroll
                    for (int j = 0; j < TN; ++j)
                        acc[i][j] += a[i] * b[j];
            }
            __syncthreads();
        }
    }

    #pragma unroll
    for (int i = 0; i < TM; ++i) {
        int row = mBase + ty * TM + i;
        if (row >= M) continue;
        #pragma unroll
        for (int j = 0; j < TN; j += 4) {
            int colc = nBase + tx * TN + j;
            float4 o = make_float4(acc[i][j], acc[i][j + 1], acc[i][j + 2], acc[i][j + 3]);
            if (bias) {
                o.x += bias[colc]; o.y += bias[colc + 1];
                o.z += bias[colc + 2]; o.w += bias[colc + 3];
            }
            *(float4*)&C[(size_t)row * NN + colc] = o;
        }
    }
}

// ---------------- BatchNorm ----------------
template<int C>
__global__ void k_colstats(const float* __restrict__ X, float* __restrict__ sum, float* __restrict__ sq) {
    constexpr int RPB = 256 / C;
    int tid = threadIdx.x;
    int c = tid % C;
    int r0 = blockIdx.x * RPB + tid / C;
    float s = 0.f, q = 0.f;
    for (int r = r0; r < N_NODES; r += gridDim.x * RPB) {
        float v = X[(size_t)r * C + c];
        s += v; q += v * v;
    }
    atomicAdd(&sum[c], s);
    atomicAdd(&sq[c], q);
}

template<int C>
__global__ void k_finstats(const float* __restrict__ sum, const float* __restrict__ sq,
                           const float* __restrict__ g, const float* __restrict__ be,
                           float* __restrict__ A, float* __restrict__ B) {
    int c = threadIdx.x;
    if (c < C) {
        float mu = sum[c] * (1.f / N_NODES);
        float var = sq[c] * (1.f / N_NODES) - mu * mu;
        float a = g[c] * rsqrtf(var + BN_EPS);
        A[c] = a;
        B[c] = be[c] - a * mu;
    }
}

template<int C>
__global__ void k_bnrelu(float* __restrict__ X, const float* __restrict__ A, const float* __restrict__ B) {
    size_t total4 = (size_t)N_NODES * C / 4;
    for (size_t i = blockIdx.x * (size_t)blockDim.x + threadIdx.x; i < total4;
         i += (size_t)gridDim.x * blockDim.x) {
        int c4 = (int)((i * 4) % C);
        float4 x = ((float4*)X)[i];
        float4 a = *(const float4*)&A[c4];
        float4 b = *(const float4*)&B[c4];
        x.x = fmaxf(a.x * x.x + b.x, 0.f);
        x.y = fmaxf(a.y * x.y + b.y, 0.f);
        x.z = fmaxf(a.z * x.z + b.z, 0.f);
        x.w = fmaxf(a.w * x.w + b.w, 0.f);
        ((float4*)X)[i] = x;
    }
}

// ---------------- GAT attention coefficients ----------------
__global__ void __launch_bounds__(256) k_attn(const float* __restrict__ xp,
                                              const float* __restrict__ att_src,
                                              const float* __restrict__ att_dst,
                                              float* __restrict__ att) {
    int lane = threadIdx.x & 63;
    int i = (blockIdx.x << 2) + (threadIdx.x >> 6);
    if (i >= N_NODES) return;
    #pragma unroll
    for (int h = 0; h < 4; ++h) {
        float v = xp[(size_t)i * 256 + h * 64 + lane];
        float s = v * att_src[h * 64 + lane];
        float d = v * att_dst[h * 64 + lane];
        #pragma unroll
        for (int o = 32; o; o >>= 1) {
            s += __shfl_xor(s, o);
            d += __shfl_xor(d, o);
        }
        if (lane == 0) { att[i * 8 + h] = s; att[i * 8 + 4 + h] = d; }
    }
}

// ---------------- GAT softmax + aggregate + head-mean + relu + node-mean ----------------
__global__ void __launch_bounds__(256) k_gat(const float* __restrict__ xp,
                                             const float* __restrict__ att,
                                             const int* __restrict__ rowptr,
                                             const int* __restrict__ col,
                                             const float* __restrict__ bg,
                                             float* __restrict__ accout) {
    __shared__ float bsum[64];
    int tid = threadIdx.x;
    if (tid < 64) bsum[tid] = 0.f;
    __syncthreads();
    int lane = tid & 63;
    int gw = (blockIdx.x << 2) + (tid >> 6);
    int stride = gridDim.x << 2;
    float ysum = 0.f;
    float bgl = bg[lane];
    for (int i = gw; i < N_NODES; i += stride) {
        int b = rowptr[i], e = rowptr[i + 1];
        float4 ai = *(const float4*)(att + (size_t)i * 8);      // a_src[i]
        float4 ad = *(const float4*)(att + (size_t)i * 8 + 4);  // a_dst[i]
        float es[4], m[4];
        es[0] = lrelu(ai.x + ad.x); es[1] = lrelu(ai.y + ad.y);
        es[2] = lrelu(ai.z + ad.z); es[3] = lrelu(ai.w + ad.w);
        m[0] = es[0]; m[1] = es[1]; m[2] = es[2]; m[3] = es[3];
        for (int p = b; p < e; ++p) {
            int j = col[p];
            float4 aj = *(const float4*)(att + (size_t)j * 8);
            m[0] = fmaxf(m[0], lrelu(aj.x + ad.x));
            m[1] = fmaxf(m[1], lrelu(aj.y + ad.y));
            m[2] = fmaxf(m[2], lrelu(aj.z + ad.z));
            m[3] = fmaxf(m[3], lrelu(aj.w + ad.w));
        }
        const float* xpi = xp + (size_t)i * 256 + lane;
        float s[4], acc[4];
        #pragma unroll
        for (int h = 0; h < 4; ++h) {
            float w = __expf(es[h] - m[h]);
            s[h] = w;
            acc[h] = w * xpi[h * 64];
        }
        for (int p = b; p < e; ++p) {
            int j = col[p];
            float4 aj = *(const float4*)(att + (size_t)j * 8);
            const float* xpj = xp + (size_t)j * 256 + lane;
            float w0 = __expf(lrelu(aj.x + ad.x) - m[0]); s[0] += w0; acc[0] += w0 * xpj[0];
            float w1 = __expf(lrelu(aj.y + ad.y) - m[1]); s[1] += w1; acc[1] += w1 * xpj[64];
            float w2 = __expf(lrelu(aj.z + ad.z) - m[2]); s[2] += w2; acc[2] += w2 * xpj[128];
            float w3 = __expf(lrelu(aj.w + ad.w) - m[3]); s[3] += w3; acc[3] += w3 * xpj[192];
        }
        float y = 0.25f * (acc[0] / s[0] + acc[1] / s[1] + acc[2] / s[2] + acc[3] / s[3]) + bgl;
        ysum += fmaxf(y, 0.f);
    }
    atomicAdd(&bsum[lane], ysum);
    __syncthreads();
    if (tid < 64) atomicAdd(accout + tid, bsum[tid]);
}

__global__ void k_final(const float* __restrict__ accout, float* __restrict__ out) {
    int d = threadIdx.x;
    if (d < 64) out[d] = accout[d] * (1.f / N_NODES);
}

// ---------------- launch ----------------
extern "C" void kernel_launch(void* const* d_in, const int* in_sizes, int n_in,
                              void* d_out, int out_size, void* d_ws, size_t ws_size,
                              hipStream_t stream) {
    const float* x       = (const float*)d_in[0];
    const int*   ei      = (const int*)d_in[1];
    const float* W1l     = (const float*)d_in[2];
    const float* b1l     = (const float*)d_in[3];
    const float* W1r     = (const float*)d_in[4];
    const float* W2l     = (const float*)d_in[5];
    const float* b2l     = (const float*)d_in[6];
    const float* W2r     = (const float*)d_in[7];
    const float* g1      = (const float*)d_in[8];
    const float* be1     = (const float*)d_in[9];
    const float* g2      = (const float*)d_in[10];
    const float* be2     = (const float*)d_in[11];
    const float* Wg      = (const float*)d_in[12];
    const float* att_src = (const float*)d_in[13];
    const float* att_dst = (const float*)d_in[14];
    const float* bg      = (const float*)d_in[15];
    float* out = (float*)d_out;

    char* p = (char*)d_ws;
    auto alloc = [&](size_t bytes) -> char* {
        char* q = p;
        p += (bytes + 255) & ~(size_t)255;
        return q;
    };
    int*   cnt    = (int*)alloc((size_t)N_NODES * 4);
    float* stats  = (float*)alloc(1344 * 4);
    int*   rowptr = (int*)alloc((size_t)(N_NODES + 1) * 4);
    int*   bsums  = (int*)alloc(256 * 4);
    int*   col    = (int*)alloc((size_t)N_EDGES * 4);
    float* agg1   = (float*)alloc((size_t)N_NODES * 128 * 4);
    float* h1     = (float*)alloc((size_t)N_NODES * 256 * 4);
    float* agg2   = (float*)alloc((size_t)N_NODES * 256 * 4);  // later reused as xp
    float* h2     = (float*)alloc((size_t)N_NODES * 64 * 4);
    float* att    = (float*)alloc((size_t)N_NODES * 8 * 4);

    float* sum1 = stats;        float* sq1 = stats + 256;
    float* A1s  = stats + 512;  float* B1s = stats + 768;
    float* sum2 = stats + 1024; float* sq2 = stats + 1088;
    float* A2s  = stats + 1152; float* B2s = stats + 1216;
    float* accout = stats + 1280;

    const int* srcA = ei;
    const int* dstA = ei + N_EDGES;

    // CSR build
    k_init_zero<<<118, 256, 0, stream>>>(cnt, stats);
    k_count<<<(N_EDGES + 255) / 256, 256, 0, stream>>>(dstA, cnt);
    k_scan1<<<118, 256, 0, stream>>>(cnt, rowptr, bsums);
    k_scan2<<<1, 128, 0, stream>>>(bsums, 118);
    k_scan3<<<118, 256, 0, stream>>>(rowptr, bsums, cnt);
    k_fill<<<(N_EDGES + 255) / 256, 256, 0, stream>>>(srcA, dstA, rowptr, cnt, col);

    // SAGE layer 1
    k_sage_agg<128><<<(N_NODES + 3) / 4, 256, 0, stream>>>(x, rowptr, col, agg1);
    k_gemm<8, 8><<<dim3(235, 2), 256, 0, stream>>>(agg1, W1l, 128, x, W1r, 128, b1l, h1, N_NODES, 256);
    k_colstats<256><<<120, 256, 0, stream>>>(h1, sum1, sq1);
    k_finstats<256><<<1, 256, 0, stream>>>(sum1, sq1, g1, be1, A1s, B1s);
    k_bnrelu<256><<<1024, 256, 0, stream>>>(h1, A1s, B1s);

    // SAGE layer 2
    k_sage_agg<256><<<(N_NODES + 3) / 4, 256, 0, stream>>>(h1, rowptr, col, agg2);
    k_gemm<8, 4><<<dim3(235, 1), 256, 0, stream>>>(agg2, W2l, 256, h1, W2r, 256, b2l, h2, N_NODES, 64);
    k_colstats<64><<<120, 256, 0, stream>>>(h2, sum2, sq2);
    k_finstats<64><<<1, 64, 0, stream>>>(sum2, sq2, g2, be2, A2s, B2s);
    k_bnrelu<64><<<512, 256, 0, stream>>>(h2, A2s, B2s);

    // GAT
    float* xp = agg2;  // agg2 is dead after gemm2; reuse as xp
    k_gemm<8, 8><<<dim3(235, 2), 256, 0, stream>>>(h2, Wg, 64, nullptr, nullptr, 0, nullptr, xp, N_NODES, 256);
    k_attn<<<(N_NODES + 3) / 4, 256, 0, stream>>>(xp, att_src, att_dst, att);
    k_gat<<<2048, 256, 0, stream>>>(xp, att, rowptr, col, bg, accout);
    k_final<<<1, 64, 0, stream>>>(accout, out);
}

// Round 4
// 471.703 us; speedup vs baseline: 1.2173x; 1.0414x over previous
//
#include <hip/hip_runtime.h>
#include <hip/hip_bf16.h>
#include <stdint.h>

#define N_NODES 30000
#define N_EDGES 300000
#define D_IN    128
#define D_HID   256
#define D_OUTF  64
#define BN_EPS  1e-5f
#define NEG_SLOPE 0.2f

__device__ __forceinline__ float lrelu(float a) { return fmaxf(a, NEG_SLOPE * a); }

// ---------------- CSR build ----------------
__global__ void k_init_zero(int* cnt, float* stats) {
    int i = blockIdx.x * 256 + threadIdx.x;
    if (i < N_NODES) cnt[i] = 0;
    if (i < 1344) stats[i] = 0.f;
}

__global__ void k_count(const int* __restrict__ dst, int* __restrict__ cnt) {
    int e = blockIdx.x * 256 + threadIdx.x;
    if (e < N_EDGES) atomicAdd(&cnt[dst[e]], 1);
}

__global__ void k_scan1(const int* __restrict__ cnt, int* __restrict__ rowptr, int* __restrict__ bsums) {
    __shared__ int s[256];
    int tid = threadIdx.x;
    int idx = blockIdx.x * 256 + tid;
    int val = (idx < N_NODES) ? cnt[idx] : 0;
    s[tid] = val; __syncthreads();
    for (int o = 1; o < 256; o <<= 1) {
        int add = (tid >= o) ? s[tid - o] : 0;
        __syncthreads();
        s[tid] += add;
        __syncthreads();
    }
    if (idx < N_NODES) rowptr[idx] = s[tid] - val;  // exclusive (local)
    if (tid == 255) bsums[blockIdx.x] = s[255];
}

__global__ void k_scan2(int* bsums, int nb) {
    __shared__ int s[128];
    int tid = threadIdx.x;
    int val = (tid < nb) ? bsums[tid] : 0;
    s[tid] = val; __syncthreads();
    for (int o = 1; o < 128; o <<= 1) {
        int add = (tid >= o) ? s[tid - o] : 0;
        __syncthreads();
        s[tid] += add;
        __syncthreads();
    }
    if (tid < nb) bsums[tid] = s[tid] - val;  // exclusive
}

__global__ void k_scan3(int* __restrict__ rowptr, const int* __restrict__ bsums, int* __restrict__ cnt) {
    int idx = blockIdx.x * 256 + threadIdx.x;
    if (idx < N_NODES) { rowptr[idx] += bsums[idx >> 8]; cnt[idx] = 0; }
    if (idx == 0) rowptr[N_NODES] = N_EDGES;
}

__global__ void k_fill(const int* __restrict__ srcA, const int* __restrict__ dstA,
                       const int* __restrict__ rowptr, int* __restrict__ cnt, int* __restrict__ col) {
    int e = blockIdx.x * 256 + threadIdx.x;
    if (e < N_EDGES) {
        int d = dstA[e];
        int pos = rowptr[d] + atomicAdd(&cnt[d], 1);
        col[pos] = srcA[e];
    }
}

// ---------------- SAGE mean aggregation: one wave per node ----------------
template<int D>
__global__ void __launch_bounds__(256) k_sage_agg(const float* __restrict__ X,
                                                  const int* __restrict__ rowptr,
                                                  const int* __restrict__ col,
                                                  float* __restrict__ out) {
    constexpr int V = D / 64;
    int lane = threadIdx.x & 63;
    int i = (blockIdx.x << 2) + (threadIdx.x >> 6);
    if (i >= N_NODES) return;
    int b = rowptr[i], e = rowptr[i + 1];
    float acc[V] = {};
    for (int p = b; p < e; ++p) {
        int j = col[p];
        if constexpr (V == 2) {
            float2 v = *(const float2*)(X + (size_t)j * D + lane * 2);
            acc[0] += v.x; acc[1] += v.y;
        } else {
            float4 v = *(const float4*)(X + (size_t)j * D + lane * 4);
            acc[0] += v.x; acc[1] += v.y; acc[2] += v.z; acc[3] += v.w;
        }
    }
    float inv = 1.f / fmaxf((float)(e - b), 1.f);
    if constexpr (V == 2) {
        *(float2*)(out + (size_t)i * D + lane * 2) = make_float2(acc[0] * inv, acc[1] * inv);
    } else {
        *(float4*)(out + (size_t)i * D + lane * 4) =
            make_float4(acc[0] * inv, acc[1] * inv, acc[2] * inv, acc[3] * inv);
    }
}

// ---------------- dual GEMM: C = A1@B1 + A2@B2 + bias ----------------
// A: [M,K] row-major, B: [K,NN] row-major, C: [M,NN] (fp32 or bf16 out)
template<int TM, int TN, bool BF16OUT>
__global__ void __launch_bounds__(256) k_gemm(const float* __restrict__ A1, const float* __restrict__ B1, int K1,
                                              const float* __restrict__ A2, const float* __restrict__ B2, int K2,
                                              const float* __restrict__ bias, void* __restrict__ Cv,
                                              int M, int NN) {
    constexpr int BM = TM * 16, BN = TN * 16, BK = 16;
    __shared__ float As[BK][BM + 4];
    __shared__ float Bs[BK][BN + 4];
    int tid = threadIdx.x;
    int ty = tid >> 4, tx = tid & 15;
    int mBase = blockIdx.x * BM, nBase = blockIdx.y * BN;
    float acc[TM][TN] = {};

    for (int pair = 0; pair < 2; ++pair) {
        const float* A = pair ? A2 : A1;
        const float* B = pair ? B2 : B1;
        int K = pair ? K2 : K1;
        if (K == 0) break;
        for (int k0 = 0; k0 < K; k0 += BK) {
            constexpr int AV = BM * BK / (256 * 4);
            #pragma unroll
            for (int v = 0; v < AV; ++v) {
                int l = tid + v * 256;
                int r = l >> 2;
                int c = (l & 3) << 2;
                int row = mBase + r;
                float4 val = (row < M) ? *(const float4*)&A[(size_t)row * K + k0 + c]
                                       : make_float4(0.f, 0.f, 0.f, 0.f);
                As[c + 0][r] = val.x; As[c + 1][r] = val.y;
                As[c + 2][r] = val.z; As[c + 3][r] = val.w;
            }
            constexpr int BV = BN * BK / (256 * 4);
            #pragma unroll
            for (int v = 0; v < BV; ++v) {
                int l = tid + v * 256;
                int r = l / (BN / 4);
                int c = (l % (BN / 4)) * 4;
                float4 val = *(const float4*)&B[(size_t)(k0 + r) * NN + nBase + c];
                *(float4*)&Bs[r][c] = val;
            }
            __syncthreads();
            #pragma unroll
            for (int kk = 0; kk < BK; ++kk) {
                float a[TM], b[TN];
                #pragma unroll
                for (int i = 0; i < TM; ++i) a[i] = As[kk][ty * TM + i];
                #pragma unroll
                for (int j = 0; j < TN; ++j) b[j] = Bs[kk][tx * TN + j];
                #pragma unroll
                for (int i = 0; i < TM; ++i)
                    #pragma unroll
                    for (int j = 0; j < TN; ++j)
                        acc[i][j] += a[i] * b[j];
            }
            __syncthreads();
        }
    }

    #pragma unroll
    for (int i = 0; i < TM; ++i) {
        int row = mBase + ty * TM + i;
        if (row >= M) continue;
        #pragma unroll
        for (int j = 0; j < TN; j += 4) {
            int colc = nBase + tx * TN + j;
            float4 o = make_float4(acc[i][j], acc[i][j + 1], acc[i][j + 2], acc[i][j + 3]);
            if (bias) {
                o.x += bias[colc]; o.y += bias[colc + 1];
                o.z += bias[colc + 2]; o.w += bias[colc + 3];
            }
            if constexpr (BF16OUT) {
                __hip_bfloat16* Cb = (__hip_bfloat16*)Cv;
                __hip_bfloat16 t[4] = {__float2bfloat16(o.x), __float2bfloat16(o.y),
                                       __float2bfloat16(o.z), __float2bfloat16(o.w)};
                *(ushort4*)&Cb[(size_t)row * NN + colc] = *(ushort4*)t;
            } else {
                float* C = (float*)Cv;
                *(float4*)&C[(size_t)row * NN + colc] = o;
            }
        }
    }
}

// ---------------- BatchNorm ----------------
template<int C>
__global__ void k_colstats(const float* __restrict__ X, float* __restrict__ sum, float* __restrict__ sq) {
    constexpr int RPB = 256 / C;
    int tid = threadIdx.x;
    int c = tid % C;
    int r0 = blockIdx.x * RPB + tid / C;
    float s = 0.f, q = 0.f;
    for (int r = r0; r < N_NODES; r += gridDim.x * RPB) {
        float v = X[(size_t)r * C + c];
        s += v; q += v * v;
    }
    atomicAdd(&sum[c], s);
    atomicAdd(&sq[c], q);
}

template<int C>
__global__ void k_finstats(const float* __restrict__ sum, const float* __restrict__ sq,
                           const float* __restrict__ g, const float* __restrict__ be,
                           float* __restrict__ A, float* __restrict__ B) {
    int c = threadIdx.x;
    if (c < C) {
        float mu = sum[c] * (1.f / N_NODES);
        float var = sq[c] * (1.f / N_NODES) - mu * mu;
        float a = g[c] * rsqrtf(var + BN_EPS);
        A[c] = a;
        B[c] = be[c] - a * mu;
    }
}

template<int C>
__global__ void k_bnrelu(float* __restrict__ X, const float* __restrict__ A, const float* __restrict__ B) {
    size_t total4 = (size_t)N_NODES * C / 4;
    for (size_t i = blockIdx.x * (size_t)blockDim.x + threadIdx.x; i < total4;
         i += (size_t)gridDim.x * blockDim.x) {
        int c4 = (int)((i * 4) % C);
        float4 x = ((float4*)X)[i];
        float4 a = *(const float4*)&A[c4];
        float4 b = *(const float4*)&B[c4];
        x.x = fmaxf(a.x * x.x + b.x, 0.f);
        x.y = fmaxf(a.y * x.y + b.y, 0.f);
        x.z = fmaxf(a.z * x.z + b.z, 0.f);
        x.w = fmaxf(a.w * x.w + b.w, 0.f);
        ((float4*)X)[i] = x;
    }
}

// ---------------- GAT attention coefficients (bf16 xp) ----------------
__global__ void __launch_bounds__(256) k_attn(const __hip_bfloat16* __restrict__ xp,
                                              const float* __restrict__ att_src,
                                              const float* __restrict__ att_dst,
                                              float* __restrict__ att) {
    int lane = threadIdx.x & 63;
    int i = (blockIdx.x << 2) + (threadIdx.x >> 6);
    if (i >= N_NODES) return;
    #pragma unroll
    for (int h = 0; h < 4; ++h) {
        float v = __bfloat162float(xp[(size_t)i * 256 + h * 64 + lane]);
        float s = v * att_src[h * 64 + lane];
        float d = v * att_dst[h * 64 + lane];
        #pragma unroll
        for (int o = 32; o; o >>= 1) {
            s += __shfl_xor(s, o);
            d += __shfl_xor(d, o);
        }
        if (lane == 0) { att[i * 8 + h] = s; att[i * 8 + 4 + h] = d; }
    }
}

// ---------------- GAT: online softmax + aggregate + head-mean + relu + node-mean ----------------
__global__ void __launch_bounds__(256) k_gat(const __hip_bfloat16* __restrict__ xp,
                                             const float* __restrict__ att,
                                             const int* __restrict__ rowptr,
                                             const int* __restrict__ col,
                                             const float* __restrict__ bg,
                                             float* __restrict__ accout) {
    __shared__ float bsum[64];
    int tid = threadIdx.x;
    if (tid < 64) bsum[tid] = 0.f;
    __syncthreads();
    int lane = tid & 63;
    int gw = (blockIdx.x << 2) + (tid >> 6);
    int stride = gridDim.x << 2;
    float ysum = 0.f;
    float bgl = bg[lane];
    for (int i = gw; i < N_NODES; i += stride) {
        int b = rowptr[i], e = rowptr[i + 1];
        float4 ai = *(const float4*)(att + (size_t)i * 8);      // a_src[i]
        float4 ad = *(const float4*)(att + (size_t)i * 8 + 4);  // a_dst[i]
        const __hip_bfloat16* xpi = xp + (size_t)i * 256 + lane;
        // init with self-loop edge (i -> i): w = 1, m = e_self
        float m[4], s[4], acc[4];
        m[0] = lrelu(ai.x + ad.x); m[1] = lrelu(ai.y + ad.y);
        m[2] = lrelu(ai.z + ad.z); m[3] = lrelu(ai.w + ad.w);
        #pragma unroll
        for (int h = 0; h < 4; ++h) {
            s[h] = 1.f;
            acc[h] = __bfloat162float(xpi[h * 64]);
        }
        for (int p = b; p < e; ++p) {
            int j = col[p];
            float4 aj = *(const float4*)(att + (size_t)j * 8);
            const __hip_bfloat16* xpj = xp + (size_t)j * 256 + lane;
            float x0 = __bfloat162float(xpj[0]);
            float x1 = __bfloat162float(xpj[64]);
            float x2 = __bfloat162float(xpj[128]);
            float x3 = __bfloat162float(xpj[192]);
            float e0 = lrelu(aj.x + ad.x);
            float e1 = lrelu(aj.y + ad.y);
            float e2 = lrelu(aj.z + ad.z);
            float e3 = lrelu(aj.w + ad.w);
            // online softmax update (lane-uniform scales; no divergence)
            float mn, sc, w;
            mn = fmaxf(m[0], e0); sc = __expf(m[0] - mn); w = __expf(e0 - mn);
            s[0] = s[0] * sc + w; acc[0] = acc[0] * sc + w * x0; m[0] = mn;
            mn = fmaxf(m[1], e1); sc = __expf(m[1] - mn); w = __expf(e1 - mn);
            s[1] = s[1] * sc + w; acc[1] = acc[1] * sc + w * x1; m[1] = mn;
            mn = fmaxf(m[2], e2); sc = __expf(m[2] - mn); w = __expf(e2 - mn);
            s[2] = s[2] * sc + w; acc[2] = acc[2] * sc + w * x2; m[2] = mn;
            mn = fmaxf(m[3], e3); sc = __expf(m[3] - mn); w = __expf(e3 - mn);
            s[3] = s[3] * sc + w; acc[3] = acc[3] * sc + w * x3; m[3] = mn;
        }
        float y = 0.25f * (acc[0] / s[0] + acc[1] / s[1] + acc[2] / s[2] + acc[3] / s[3]) + bgl;
        ysum += fmaxf(y, 0.f);
    }
    atomicAdd(&bsum[lane], ysum);
    __syncthreads();
    if (tid < 64) atomicAdd(accout + tid, bsum[tid]);
}

__global__ void k_final(const float* __restrict__ accout, float* __restrict__ out) {
    int d = threadIdx.x;
    if (d < 64) out[d] = accout[d] * (1.f / N_NODES);
}

// ---------------- launch ----------------
extern "C" void kernel_launch(void* const* d_in, const int* in_sizes, int n_in,
                              void* d_out, int out_size, void* d_ws, size_t ws_size,
                              hipStream_t stream) {
    const float* x       = (const float*)d_in[0];
    const int*   ei      = (const int*)d_in[1];
    const float* W1l     = (const float*)d_in[2];
    const float* b1l     = (const float*)d_in[3];
    const float* W1r     = (const float*)d_in[4];
    const float* W2l     = (const float*)d_in[5];
    const float* b2l     = (const float*)d_in[6];
    const float* W2r     = (const float*)d_in[7];
    const float* g1      = (const float*)d_in[8];
    const float* be1     = (const float*)d_in[9];
    const float* g2      = (const float*)d_in[10];
    const float* be2     = (const float*)d_in[11];
    const float* Wg      = (const float*)d_in[12];
    const float* att_src = (const float*)d_in[13];
    const float* att_dst = (const float*)d_in[14];
    const float* bg      = (const float*)d_in[15];
    float* out = (float*)d_out;

    char* p = (char*)d_ws;
    auto alloc = [&](size_t bytes) -> char* {
        char* q = p;
        p += (bytes + 255) & ~(size_t)255;
        return q;
    };
    int*   cnt    = (int*)alloc((size_t)N_NODES * 4);
    float* stats  = (float*)alloc(1344 * 4);
    int*   rowptr = (int*)alloc((size_t)(N_NODES + 1) * 4);
    int*   bsums  = (int*)alloc(256 * 4);
    int*   col    = (int*)alloc((size_t)N_EDGES * 4);
    float* agg1   = (float*)alloc((size_t)N_NODES * 128 * 4);
    float* h1     = (float*)alloc((size_t)N_NODES * 256 * 4);
    float* agg2   = (float*)alloc((size_t)N_NODES * 256 * 4);  // later reused as xp (bf16)
    float* h2     = (float*)alloc((size_t)N_NODES * 64 * 4);
    float* att    = (float*)alloc((size_t)N_NODES * 8 * 4);

    float* sum1 = stats;        float* sq1 = stats + 256;
    float* A1s  = stats + 512;  float* B1s = stats + 768;
    float* sum2 = stats + 1024; float* sq2 = stats + 1088;
    float* A2s  = stats + 1152; float* B2s = stats + 1216;
    float* accout = stats + 1280;

    const int* srcA = ei;
    const int* dstA = ei + N_EDGES;

    // CSR build
    k_init_zero<<<118, 256, 0, stream>>>(cnt, stats);
    k_count<<<(N_EDGES + 255) / 256, 256, 0, stream>>>(dstA, cnt);
    k_scan1<<<118, 256, 0, stream>>>(cnt, rowptr, bsums);
    k_scan2<<<1, 128, 0, stream>>>(bsums, 118);
    k_scan3<<<118, 256, 0, stream>>>(rowptr, bsums, cnt);
    k_fill<<<(N_EDGES + 255) / 256, 256, 0, stream>>>(srcA, dstA, rowptr, cnt, col);

    // SAGE layer 1
    k_sage_agg<128><<<(N_NODES + 3) / 4, 256, 0, stream>>>(x, rowptr, col, agg1);
    k_gemm<8, 8, false><<<dim3(235, 2), 256, 0, stream>>>(agg1, W1l, 128, x, W1r, 128, b1l, h1, N_NODES, 256);
    k_colstats<256><<<120, 256, 0, stream>>>(h1, sum1, sq1);
    k_finstats<256><<<1, 256, 0, stream>>>(sum1, sq1, g1, be1, A1s, B1s);
    k_bnrelu<256><<<1024, 256, 0, stream>>>(h1, A1s, B1s);

    // SAGE layer 2
    k_sage_agg<256><<<(N_NODES + 3) / 4, 256, 0, stream>>>(h1, rowptr, col, agg2);
    k_gemm<8, 4, false><<<dim3(235, 1), 256, 0, stream>>>(agg2, W2l, 256, h1, W2r, 256, b2l, h2, N_NODES, 64);
    k_colstats<64><<<120, 256, 0, stream>>>(h2, sum2, sq2);
    k_finstats<64><<<1, 64, 0, stream>>>(sum2, sq2, g2, be2, A2s, B2s);
    k_bnrelu<64><<<512, 256, 0, stream>>>(h2, A2s, B2s);

    // GAT: project to xp in bf16 (halves gather traffic in k_attn / k_gat)
    __hip_bfloat16* xp = (__hip_bfloat16*)agg2;  // agg2 dead after gemm2; 15.4 MB < 30.7 MB
    k_gemm<8, 8, true><<<dim3(235, 2), 256, 0, stream>>>(h2, Wg, 64, nullptr, nullptr, 0, nullptr, xp, N_NODES, 256);
    k_attn<<<(N_NODES + 3) / 4, 256, 0, stream>>>(xp, att_src, att_dst, att);
    k_gat<<<2048, 256, 0, stream>>>(xp, att, rowptr, col, bg, accout);
    k_final<<<1, 64, 0, stream>>>(accout, out);
}

// Round 5
// 366.186 us; speedup vs baseline: 1.5681x; 1.2882x over previous
//
#include <hip/hip_runtime.h>
#include <stdint.h>

#define N_NODES 30000
#define N_EDGES 300000
#define BN_EPS  1e-5f
#define NEG_SLOPE 0.2f

typedef __attribute__((ext_vector_type(8))) short          s16x8;
typedef __attribute__((ext_vector_type(8))) unsigned short u16x8;
typedef __attribute__((ext_vector_type(4))) float          f32x4;

__device__ __forceinline__ float b2f(unsigned int u) { return __uint_as_float(u << 16); }
__device__ __forceinline__ unsigned short f2b(float f) {
    unsigned int u = __float_as_uint(f);
    return (unsigned short)((u + 0x7fffu + ((u >> 16) & 1u)) >> 16);
}
__device__ __forceinline__ float lrelu(float a) { return fmaxf(a, NEG_SLOPE * a); }

// ---------------- CSR build ----------------
__global__ void k_init_zero(int* cnt, float* stats) {
    int i = blockIdx.x * 256 + threadIdx.x;
    if (i < N_NODES) cnt[i] = 0;
    if (i < 1344) stats[i] = 0.f;
}

__global__ void k_count(const int* __restrict__ dst, int* __restrict__ cnt) {
    int e = blockIdx.x * 256 + threadIdx.x;
    if (e < N_EDGES) atomicAdd(&cnt[dst[e]], 1);
}

__global__ void k_scan1(const int* __restrict__ cnt, int* __restrict__ rowptr, int* __restrict__ bsums) {
    __shared__ int s[256];
    int tid = threadIdx.x;
    int idx = blockIdx.x * 256 + tid;
    int val = (idx < N_NODES) ? cnt[idx] : 0;
    s[tid] = val; __syncthreads();
    for (int o = 1; o < 256; o <<= 1) {
        int add = (tid >= o) ? s[tid - o] : 0;
        __syncthreads();
        s[tid] += add;
        __syncthreads();
    }
    if (idx < N_NODES) rowptr[idx] = s[tid] - val;
    if (tid == 255) bsums[blockIdx.x] = s[255];
}

__global__ void k_scan2(int* bsums, int nb) {
    __shared__ int s[128];
    int tid = threadIdx.x;
    int val = (tid < nb) ? bsums[tid] : 0;
    s[tid] = val; __syncthreads();
    for (int o = 1; o < 128; o <<= 1) {
        int add = (tid >= o) ? s[tid - o] : 0;
        __syncthreads();
        s[tid] += add;
        __syncthreads();
    }
    if (tid < nb) bsums[tid] = s[tid] - val;
}

__global__ void k_scan3(int* __restrict__ rowptr, const int* __restrict__ bsums, int* __restrict__ cnt) {
    int idx = blockIdx.x * 256 + threadIdx.x;
    if (idx < N_NODES) { rowptr[idx] += bsums[idx >> 8]; cnt[idx] = 0; }
    if (idx == 0) rowptr[N_NODES] = N_EDGES;
}

__global__ void k_fill(const int* __restrict__ srcA, const int* __restrict__ dstA,
                       const int* __restrict__ rowptr, int* __restrict__ cnt, int* __restrict__ col) {
    int e = blockIdx.x * 256 + threadIdx.x;
    if (e < N_EDGES) {
        int d = dstA[e];
        int pos = rowptr[d] + atomicAdd(&cnt[d], 1);
        col[pos] = srcA[e];
    }
}

// ---------------- conversions ----------------
__global__ void k_cvt_x(const float* __restrict__ x, unsigned short* __restrict__ xb) {
    int i = blockIdx.x * 256 + threadIdx.x;
    if (i < N_NODES * 128 / 4) {
        float4 v = ((const float4*)x)[i];
        unsigned int lo = f2b(v.x) | ((unsigned int)f2b(v.y) << 16);
        unsigned int hi = f2b(v.z) | ((unsigned int)f2b(v.w) << 16);
        ((uint2*)xb)[i] = make_uint2(lo, hi);
    }
}

// transpose-convert all 5 weights: W [K,NN] fp32 -> Wt [NN,K] bf16
__global__ void k_cvtW(const float* __restrict__ W1l, const float* __restrict__ W1r,
                       const float* __restrict__ W2l, const float* __restrict__ W2r,
                       const float* __restrict__ Wg,
                       unsigned short* __restrict__ t1l, unsigned short* __restrict__ t1r,
                       unsigned short* __restrict__ t2l, unsigned short* __restrict__ t2r,
                       unsigned short* __restrict__ tg) {
    int i = blockIdx.x * 256 + threadIdx.x;
    const float* S; unsigned short* D; int K, NN, off;
    if (i < 32768)      { S = W1l; D = t1l; K = 128; NN = 256; off = 0; }
    else if (i < 65536) { S = W1r; D = t1r; K = 128; NN = 256; off = 32768; }
    else if (i < 81920) { S = W2l; D = t2l; K = 256; NN = 64;  off = 65536; }
    else if (i < 98304) { S = W2r; D = t2r; K = 256; NN = 64;  off = 81920; }
    else if (i < 114688){ S = Wg;  D = tg;  K = 64;  NN = 256; off = 98304; }
    else return;
    int j = i - off;
    int k = j / NN, n = j % NN;
    D[n * K + k] = f2b(S[j]);
}

// ---------------- SAGE mean aggregation (bf16 in/out, fp32 accum) ----------------
template<int D>
__global__ void __launch_bounds__(256) k_sage_agg_b(const unsigned short* __restrict__ X,
                                                    const int* __restrict__ rowptr,
                                                    const int* __restrict__ col,
                                                    unsigned short* __restrict__ out) {
    constexpr int V = D / 64;
    int lane = threadIdx.x & 63;
    int i = (blockIdx.x << 2) + (threadIdx.x >> 6);
    if (i >= N_NODES) return;
    int b = rowptr[i], e = rowptr[i + 1];
    float acc[V] = {};
    for (int p = b; p < e; ++p) {
        int j = col[p];
        const unsigned short* r = X + (size_t)j * D + lane * V;
        if constexpr (V == 2) {
            unsigned int v = *(const unsigned int*)r;
            acc[0] += b2f(v & 0xffffu); acc[1] += b2f(v >> 16);
        } else {
            uint2 v = *(const uint2*)r;
            acc[0] += b2f(v.x & 0xffffu); acc[1] += b2f(v.x >> 16);
            acc[2] += b2f(v.y & 0xffffu); acc[3] += b2f(v.y >> 16);
        }
    }
    float inv = 1.f / fmaxf((float)(e - b), 1.f);
    if constexpr (V == 2) {
        unsigned int o = f2b(acc[0] * inv) | ((unsigned int)f2b(acc[1] * inv) << 16);
        *(unsigned int*)(out + (size_t)i * D + lane * 2) = o;
    } else {
        uint2 o;
        o.x = f2b(acc[0] * inv) | ((unsigned int)f2b(acc[1] * inv) << 16);
        o.y = f2b(acc[2] * inv) | ((unsigned int)f2b(acc[3] * inv) << 16);
        *(uint2*)(out + (size_t)i * D + lane * 4) = o;
    }
}

// ---------------- MFMA dual GEMM: C = A1@B1t' + A2@B2t' + bias ----------------
// A: [M,K] bf16 row-major; Bt: [NN,K] bf16 (pre-transposed weights); C: [M,NN]
template<bool BF16OUT>
__global__ void __launch_bounds__(256) k_mgemm(const unsigned short* __restrict__ A1,
                                               const unsigned short* __restrict__ Bt1, int K1,
                                               const unsigned short* __restrict__ A2,
                                               const unsigned short* __restrict__ Bt2, int K2,
                                               const float* __restrict__ bias,
                                               void* __restrict__ Cv, int M, int NN) {
    __shared__ unsigned short As[64 * 32];
    __shared__ unsigned short Bs[64 * 32];
    int tid = threadIdx.x;
    int w = tid >> 6, l = tid & 63;
    int mBase = blockIdx.x * 64, nBase = blockIdx.y * 64;
    f32x4 acc[4] = {};

    // XOR-swizzled LDS byte offset for [64][32]bf16 tiles (G4: spread 8 rows over 8 16B slots)
    auto lds_off = [](int row, int col_bf16) -> int {
        return (row * 64 + col_bf16 * 2) ^ ((row & 7) << 4);
    };
    int srow = tid >> 2;              // staging row 0..63
    int schunk = (tid & 3) << 3;      // bf16 col offset 0,8,16,24
    int s_w_off = lds_off(srow, schunk);
    int kgrp = (l >> 4) << 3;         // k-octet per lane group
    int a_off = lds_off(w * 16 + (l & 15), kgrp);
    int b_off[4];
    #pragma unroll
    for (int c = 0; c < 4; ++c) b_off[c] = lds_off(c * 16 + (l & 15), kgrp);

    for (int pair = 0; pair < 2; ++pair) {
        const unsigned short* A  = pair ? A2 : A1;
        const unsigned short* Bt = pair ? Bt2 : Bt1;
        int K = pair ? K2 : K1;
        if (K == 0) break;
        for (int k0 = 0; k0 < K; k0 += 32) {
            u16x8 av = {};
            int arow = mBase + srow;
            if (arow < M) av = *(const u16x8*)&A[(size_t)arow * K + k0 + schunk];
            u16x8 bv = *(const u16x8*)&Bt[(size_t)(nBase + srow) * K + k0 + schunk];
            *(u16x8*)((char*)As + s_w_off) = av;
            *(u16x8*)((char*)Bs + s_w_off) = bv;
            __syncthreads();
            s16x8 a = *(const s16x8*)((const char*)As + a_off);
            #pragma unroll
            for (int c = 0; c < 4; ++c) {
                s16x8 bfr = *(const s16x8*)((const char*)Bs + b_off[c]);
                acc[c] = __builtin_amdgcn_mfma_f32_16x16x32_bf16(a, bfr, acc[c], 0, 0, 0);
            }
            __syncthreads();
        }
    }

    // C/D layout (m89-verified): col = lane&15, row = (lane>>4)*4 + reg
    int colb = l & 15;
    int rbase = (l >> 4) << 2;
    #pragma unroll
    for (int c = 0; c < 4; ++c) {
        int gcol = nBase + c * 16 + colb;
        float bi = bias ? bias[gcol] : 0.f;
        #pragma unroll
        for (int r = 0; r < 4; ++r) {
            int grow = mBase + w * 16 + rbase + r;
            if (grow < M) {
                float v = acc[c][r] + bi;
                if constexpr (BF16OUT)
                    ((unsigned short*)Cv)[(size_t)grow * NN + gcol] = f2b(v);
                else
                    ((float*)Cv)[(size_t)grow * NN + gcol] = v;
            }
        }
    }
}

// ---------------- BatchNorm ----------------
template<int C>
__global__ void k_colstats(const float* __restrict__ X, float* __restrict__ sum, float* __restrict__ sq) {
    constexpr int RPB = 256 / C;
    int tid = threadIdx.x;
    int c = tid % C;
    int r0 = blockIdx.x * RPB + tid / C;
    float s = 0.f, q = 0.f;
    for (int r = r0; r < N_NODES; r += gridDim.x * RPB) {
        float v = X[(size_t)r * C + c];
        s += v; q += v * v;
    }
    atomicAdd(&sum[c], s);
    atomicAdd(&sq[c], q);
}

template<int C>
__global__ void k_finstats(const float* __restrict__ sum, const float* __restrict__ sq,
                           const float* __restrict__ g, const float* __restrict__ be,
                           float* __restrict__ A, float* __restrict__ B) {
    int c = threadIdx.x;
    if (c < C) {
        float mu = sum[c] * (1.f / N_NODES);
        float var = sq[c] * (1.f / N_NODES) - mu * mu;
        float a = g[c] * rsqrtf(var + BN_EPS);
        A[c] = a;
        B[c] = be[c] - a * mu;
    }
}

// BN + ReLU, fp32 in -> bf16 out
template<int C>
__global__ void k_bnrelu_b(const float* __restrict__ X, const float* __restrict__ A,
                           const float* __restrict__ B, unsigned short* __restrict__ Y) {
    size_t total4 = (size_t)N_NODES * C / 4;
    for (size_t i = blockIdx.x * (size_t)blockDim.x + threadIdx.x; i < total4;
         i += (size_t)gridDim.x * blockDim.x) {
        int c4 = (int)((i * 4) % C);
        float4 x = ((const float4*)X)[i];
        float4 a = *(const float4*)&A[c4];
        float4 b = *(const float4*)&B[c4];
        float o0 = fmaxf(a.x * x.x + b.x, 0.f);
        float o1 = fmaxf(a.y * x.y + b.y, 0.f);
        float o2 = fmaxf(a.z * x.z + b.z, 0.f);
        float o3 = fmaxf(a.w * x.w + b.w, 0.f);
        uint2 o;
        o.x = f2b(o0) | ((unsigned int)f2b(o1) << 16);
        o.y = f2b(o2) | ((unsigned int)f2b(o3) << 16);
        ((uint2*)Y)[i] = o;
    }
}

// ---------------- GAT attention coefficients (bf16 xp) ----------------
__global__ void __launch_bounds__(256) k_attn(const unsigned short* __restrict__ xp,
                                              const float* __restrict__ att_src,
                                              const float* __restrict__ att_dst,
                                              float* __restrict__ att) {
    int lane = threadIdx.x & 63;
    int i = (blockIdx.x << 2) + (threadIdx.x >> 6);
    if (i >= N_NODES) return;
    #pragma unroll
    for (int h = 0; h < 4; ++h) {
        float v = b2f(xp[(size_t)i * 256 + h * 64 + lane]);
        float s = v * att_src[h * 64 + lane];
        float d = v * att_dst[h * 64 + lane];
        #pragma unroll
        for (int o = 32; o; o >>= 1) {
            s += __shfl_xor(s, o);
            d += __shfl_xor(d, o);
        }
        if (lane == 0) { att[i * 8 + h] = s; att[i * 8 + 4 + h] = d; }
    }
}

// ---------------- GAT: online softmax + aggregate + head-mean + relu + node-mean ----------------
__global__ void __launch_bounds__(256) k_gat(const unsigned short* __restrict__ xp,
                                             const float* __restrict__ att,
                                             const int* __restrict__ rowptr,
                                             const int* __restrict__ col,
                                             const float* __restrict__ bg,
                                             float* __restrict__ accout) {
    __shared__ float bsum[64];
    int tid = threadIdx.x;
    if (tid < 64) bsum[tid] = 0.f;
    __syncthreads();
    int lane = tid & 63;
    int gw = (blockIdx.x << 2) + (tid >> 6);
    int stride = gridDim.x << 2;
    float ysum = 0.f;
    float bgl = bg[lane];
    for (int i = gw; i < N_NODES; i += stride) {
        int b = rowptr[i], e = rowptr[i + 1];
        float4 ai = *(const float4*)(att + (size_t)i * 8);
        float4 ad = *(const float4*)(att + (size_t)i * 8 + 4);
        const unsigned short* xpi = xp + (size_t)i * 256 + lane;
        float m[4], s[4], acc[4];
        m[0] = lrelu(ai.x + ad.x); m[1] = lrelu(ai.y + ad.y);
        m[2] = lrelu(ai.z + ad.z); m[3] = lrelu(ai.w + ad.w);
        #pragma unroll
        for (int h = 0; h < 4; ++h) {
            s[h] = 1.f;
            acc[h] = b2f(xpi[h * 64]);
        }
        for (int p = b; p < e; ++p) {
            int j = col[p];
            float4 aj = *(const float4*)(att + (size_t)j * 8);
            const unsigned short* xpj = xp + (size_t)j * 256 + lane;
            float x0 = b2f(xpj[0]);
            float x1 = b2f(xpj[64]);
            float x2 = b2f(xpj[128]);
            float x3 = b2f(xpj[192]);
            float e0 = lrelu(aj.x + ad.x);
            float e1 = lrelu(aj.y + ad.y);
            float e2 = lrelu(aj.z + ad.z);
            float e3 = lrelu(aj.w + ad.w);
            float mn, sc, wv;
            mn = fmaxf(m[0], e0); sc = __expf(m[0] - mn); wv = __expf(e0 - mn);
            s[0] = s[0] * sc + wv; acc[0] = acc[0] * sc + wv * x0; m[0] = mn;
            mn = fmaxf(m[1], e1); sc = __expf(m[1] - mn); wv = __expf(e1 - mn);
            s[1] = s[1] * sc + wv; acc[1] = acc[1] * sc + wv * x1; m[1] = mn;
            mn = fmaxf(m[2], e2); sc = __expf(m[2] - mn); wv = __expf(e2 - mn);
            s[2] = s[2] * sc + wv; acc[2] = acc[2] * sc + wv * x2; m[2] = mn;
            mn = fmaxf(m[3], e3); sc = __expf(m[3] - mn); wv = __expf(e3 - mn);
            s[3] = s[3] * sc + wv; acc[3] = acc[3] * sc + wv * x3; m[3] = mn;
        }
        float y = 0.25f * (acc[0] / s[0] + acc[1] / s[1] + acc[2] / s[2] + acc[3] / s[3]) + bgl;
        ysum += fmaxf(y, 0.f);
    }
    atomicAdd(&bsum[lane], ysum);
    __syncthreads();
    if (tid < 64) atomicAdd(accout + tid, bsum[tid]);
}

__global__ void k_final(const float* __restrict__ accout, float* __restrict__ out) {
    int d = threadIdx.x;
    if (d < 64) out[d] = accout[d] * (1.f / N_NODES);
}

// ---------------- launch ----------------
extern "C" void kernel_launch(void* const* d_in, const int* in_sizes, int n_in,
                              void* d_out, int out_size, void* d_ws, size_t ws_size,
                              hipStream_t stream) {
    const float* x       = (const float*)d_in[0];
    const int*   ei      = (const int*)d_in[1];
    const float* W1l     = (const float*)d_in[2];
    const float* b1l     = (const float*)d_in[3];
    const float* W1r     = (const float*)d_in[4];
    const float* W2l     = (const float*)d_in[5];
    const float* b2l     = (const float*)d_in[6];
    const float* W2r     = (const float*)d_in[7];
    const float* g1      = (const float*)d_in[8];
    const float* be1     = (const float*)d_in[9];
    const float* g2      = (const float*)d_in[10];
    const float* be2     = (const float*)d_in[11];
    const float* Wg      = (const float*)d_in[12];
    const float* att_src = (const float*)d_in[13];
    const float* att_dst = (const float*)d_in[14];
    const float* bg      = (const float*)d_in[15];
    float* out = (float*)d_out;

    char* p = (char*)d_ws;
    auto alloc = [&](size_t bytes) -> char* {
        char* q = p;
        p += (bytes + 255) & ~(size_t)255;
        return q;
    };
    int*   cnt    = (int*)alloc((size_t)N_NODES * 4);
    float* stats  = (float*)alloc(1344 * 4);
    int*   rowptr = (int*)alloc((size_t)(N_NODES + 1) * 4);
    int*   bsums  = (int*)alloc(256 * 4);
    int*   col    = (int*)alloc((size_t)N_EDGES * 4);
    unsigned short* xb    = (unsigned short*)alloc((size_t)N_NODES * 128 * 2);  // 7.68MB
    unsigned short* agg1b = (unsigned short*)alloc((size_t)N_NODES * 128 * 2);  // 7.68MB (contiguous after xb)
    float* h1   = (float*)alloc((size_t)N_NODES * 256 * 4);                     // 30.72MB
    unsigned short* h1b = (unsigned short*)alloc((size_t)N_NODES * 256 * 2);    // 15.36MB
    float* att  = (float*)alloc((size_t)N_NODES * 8 * 4);
    unsigned short* w1lt = (unsigned short*)alloc(128 * 256 * 2);
    unsigned short* w1rt = (unsigned short*)alloc(128 * 256 * 2);
    unsigned short* w2lt = (unsigned short*)alloc(256 * 64 * 2);
    unsigned short* w2rt = (unsigned short*)alloc(256 * 64 * 2);
    unsigned short* wgt  = (unsigned short*)alloc(64 * 256 * 2);

    // aliases (lifetimes verified):
    unsigned short* agg2b = (unsigned short*)h1;                   // h1 fp32 dead after bnrelu<256>
    float* h2  = (float*)((char*)h1 + 15360000);                   // 7.68MB fp32
    unsigned short* h2b = (unsigned short*)((char*)h1 + 23040000); // 3.84MB
    unsigned short* xp  = xb;                                      // xb+agg1b dead after gemm1 (15.36MB)

    float* sum1 = stats;        float* sq1 = stats + 256;
    float* A1s  = stats + 512;  float* B1s = stats + 768;
    float* sum2 = stats + 1024; float* sq2 = stats + 1088;
    float* A2s  = stats + 1152; float* B2s = stats + 1216;
    float* accout = stats + 1280;

    const int* srcA = ei;
    const int* dstA = ei + N_EDGES;

    // CSR build
    k_init_zero<<<118, 256, 0, stream>>>(cnt, stats);
    k_count<<<(N_EDGES + 255) / 256, 256, 0, stream>>>(dstA, cnt);
    k_scan1<<<118, 256, 0, stream>>>(cnt, rowptr, bsums);
    k_scan2<<<1, 128, 0, stream>>>(bsums, 118);
    k_scan3<<<118, 256, 0, stream>>>(rowptr, bsums, cnt);
    k_fill<<<(N_EDGES + 255) / 256, 256, 0, stream>>>(srcA, dstA, rowptr, cnt, col);

    // conversions
    k_cvt_x<<<3750, 256, 0, stream>>>(x, xb);
    k_cvtW<<<448, 256, 0, stream>>>(W1l, W1r, W2l, W2r, Wg, w1lt, w1rt, w2lt, w2rt, wgt);

    // SAGE layer 1
    k_sage_agg_b<128><<<(N_NODES + 3) / 4, 256, 0, stream>>>(xb, rowptr, col, agg1b);
    k_mgemm<false><<<dim3(469, 4), 256, 0, stream>>>(agg1b, w1lt, 128, xb, w1rt, 128, b1l, h1, N_NODES, 256);
    k_colstats<256><<<480, 256, 0, stream>>>(h1, sum1, sq1);
    k_finstats<256><<<1, 256, 0, stream>>>(sum1, sq1, g1, be1, A1s, B1s);
    k_bnrelu_b<256><<<1024, 256, 0, stream>>>(h1, A1s, B1s, h1b);

    // SAGE layer 2
    k_sage_agg_b<256><<<(N_NODES + 3) / 4, 256, 0, stream>>>(h1b, rowptr, col, agg2b);
    k_mgemm<false><<<dim3(469, 1), 256, 0, stream>>>(agg2b, w2lt, 256, h1b, w2rt, 256, b2l, h2, N_NODES, 64);
    k_colstats<64><<<480, 256, 0, stream>>>(h2, sum2, sq2);
    k_finstats<64><<<1, 64, 0, stream>>>(sum2, sq2, g2, be2, A2s, B2s);
    k_bnrelu_b<64><<<512, 256, 0, stream>>>(h2, A2s, B2s, h2b);

    // GAT projection (bf16 out), attention, aggregate
    k_mgemm<true><<<dim3(469, 4), 256, 0, stream>>>(h2b, wgt, 64, nullptr, nullptr, 0, nullptr, xp, N_NODES, 256);
    k_attn<<<(N_NODES + 3) / 4, 256, 0, stream>>>(xp, att_src, att_dst, att);
    k_gat<<<2048, 256, 0, stream>>>(xp, att, rowptr, col, bg, accout);
    k_final<<<1, 64, 0, stream>>>(accout, out);
}

// Round 6
// 335.510 us; speedup vs baseline: 1.7115x; 1.0914x over previous
//
#include <hip/hip_runtime.h>
#include <stdint.h>

#define N_NODES 30000
#define N_EDGES 300000
#define BN_EPS  1e-5f
#define NEG_SLOPE 0.2f

typedef __attribute__((ext_vector_type(8))) short          s16x8;
typedef __attribute__((ext_vector_type(8))) unsigned short u16x8;
typedef __attribute__((ext_vector_type(4))) float          f32x4;

__device__ __forceinline__ float b2f(unsigned int u) { return __uint_as_float(u << 16); }
__device__ __forceinline__ unsigned short f2b(float f) {
    unsigned int u = __float_as_uint(f);
    return (unsigned short)((u + 0x7fffu + ((u >> 16) & 1u)) >> 16);
}
__device__ __forceinline__ float lrelu(float a) { return fmaxf(a, NEG_SLOPE * a); }

// ---------------- CSR build ----------------
__global__ void k_init_zero(int* cnt, float* stats) {
    int i = blockIdx.x * 256 + threadIdx.x;
    if (i < N_NODES) cnt[i] = 0;
    if (i < 1344) stats[i] = 0.f;
}

__global__ void k_count(const int* __restrict__ dst, int* __restrict__ cnt) {
    int e = blockIdx.x * 256 + threadIdx.x;
    if (e < N_EDGES) atomicAdd(&cnt[dst[e]], 1);
}

__global__ void k_scan1(const int* __restrict__ cnt, int* __restrict__ rowptr, int* __restrict__ bsums) {
    __shared__ int s[256];
    int tid = threadIdx.x;
    int idx = blockIdx.x * 256 + tid;
    int val = (idx < N_NODES) ? cnt[idx] : 0;
    s[tid] = val; __syncthreads();
    for (int o = 1; o < 256; o <<= 1) {
        int add = (tid >= o) ? s[tid - o] : 0;
        __syncthreads();
        s[tid] += add;
        __syncthreads();
    }
    if (idx < N_NODES) rowptr[idx] = s[tid] - val;
    if (tid == 255) bsums[blockIdx.x] = s[255];
}

__global__ void k_scan2(int* bsums, int nb) {
    __shared__ int s[128];
    int tid = threadIdx.x;
    int val = (tid < nb) ? bsums[tid] : 0;
    s[tid] = val; __syncthreads();
    for (int o = 1; o < 128; o <<= 1) {
        int add = (tid >= o) ? s[tid - o] : 0;
        __syncthreads();
        s[tid] += add;
        __syncthreads();
    }
    if (tid < nb) bsums[tid] = s[tid] - val;
}

__global__ void k_scan3(int* __restrict__ rowptr, const int* __restrict__ bsums, int* __restrict__ cnt) {
    int idx = blockIdx.x * 256 + threadIdx.x;
    if (idx < N_NODES) { rowptr[idx] += bsums[idx >> 8]; cnt[idx] = 0; }
    if (idx == 0) rowptr[N_NODES] = N_EDGES;
}

__global__ void k_fill(const int* __restrict__ srcA, const int* __restrict__ dstA,
                       const int* __restrict__ rowptr, int* __restrict__ cnt, int* __restrict__ col) {
    int e = blockIdx.x * 256 + threadIdx.x;
    if (e < N_EDGES) {
        int d = dstA[e];
        int pos = rowptr[d] + atomicAdd(&cnt[d], 1);
        col[pos] = srcA[e];
    }
}

// ---------------- conversions ----------------
__global__ void k_cvt_x(const float* __restrict__ x, unsigned short* __restrict__ xb) {
    int i = blockIdx.x * 256 + threadIdx.x;
    if (i < N_NODES * 128 / 4) {
        float4 v = ((const float4*)x)[i];
        unsigned int lo = f2b(v.x) | ((unsigned int)f2b(v.y) << 16);
        unsigned int hi = f2b(v.z) | ((unsigned int)f2b(v.w) << 16);
        ((uint2*)xb)[i] = make_uint2(lo, hi);
    }
}

// transpose-convert weights -> [NN,K] bf16, plus stacked-head GAT matrix btf
__global__ void k_cvtW(const float* __restrict__ W1l, const float* __restrict__ W1r,
                       const float* __restrict__ W2l, const float* __restrict__ W2r,
                       const float* __restrict__ Wg,
                       unsigned short* __restrict__ t1l, unsigned short* __restrict__ t1r,
                       unsigned short* __restrict__ t2l, unsigned short* __restrict__ t2r,
                       unsigned short* __restrict__ btf) {
    int i = blockIdx.x * 256 + threadIdx.x;
    if (i >= 114688) return;
    if (i >= 98304) {
        // btf[n, h*64+k] = Wg[k, h*64+n] * 0.25  (head-stacked, pre-scaled by 1/H)
        int j = i - 98304;
        int n = j >> 8, r = j & 255;
        int h = r >> 6, k = r & 63;
        btf[j] = f2b(Wg[k * 256 + h * 64 + n] * 0.25f);
        return;
    }
    const float* S; unsigned short* D; int K, NN, off;
    if (i < 32768)      { S = W1l; D = t1l; K = 128; NN = 256; off = 0; }
    else if (i < 65536) { S = W1r; D = t1r; K = 128; NN = 256; off = 32768; }
    else if (i < 81920) { S = W2l; D = t2l; K = 256; NN = 64;  off = 65536; }
    else                { S = W2r; D = t2r; K = 256; NN = 64;  off = 81920; }
    int j = i - off;
    int k = j / NN, n = j % NN;
    D[n * K + k] = f2b(S[j]);
}

// v_src[h,k] = sum_d Wg[k, h*64+d] * att_src[h,d]   (and same for dst)
__global__ void k_attvec(const float* __restrict__ Wg, const float* __restrict__ att_src,
                         const float* __restrict__ att_dst, float* __restrict__ vsrc,
                         float* __restrict__ vdst) {
    int tid = threadIdx.x;
    int h = tid >> 6, k = tid & 63;
    float s = 0.f, d = 0.f;
    for (int dd = 0; dd < 64; ++dd) {
        float w = Wg[k * 256 + h * 64 + dd];
        s += w * att_src[h * 64 + dd];
        d += w * att_dst[h * 64 + dd];
    }
    vsrc[h * 64 + k] = s;
    vdst[h * 64 + k] = d;
}

// ---------------- SAGE mean aggregation (bf16 in/out, fp32 accum) ----------------
template<int D>
__global__ void __launch_bounds__(256) k_sage_agg_b(const unsigned short* __restrict__ X,
                                                    const int* __restrict__ rowptr,
                                                    const int* __restrict__ col,
                                                    unsigned short* __restrict__ out) {
    constexpr int V = D / 64;
    int lane = threadIdx.x & 63;
    int i = (blockIdx.x << 2) + (threadIdx.x >> 6);
    if (i >= N_NODES) return;
    int b = rowptr[i], e = rowptr[i + 1];
    float acc[V] = {};
    for (int p = b; p < e; ++p) {
        int j = col[p];
        const unsigned short* r = X + (size_t)j * D + lane * V;
        if constexpr (V == 2) {
            unsigned int v = *(const unsigned int*)r;
            acc[0] += b2f(v & 0xffffu); acc[1] += b2f(v >> 16);
        } else {
            uint2 v = *(const uint2*)r;
            acc[0] += b2f(v.x & 0xffffu); acc[1] += b2f(v.x >> 16);
            acc[2] += b2f(v.y & 0xffffu); acc[3] += b2f(v.y >> 16);
        }
    }
    float inv = 1.f / fmaxf((float)(e - b), 1.f);
    if constexpr (V == 2) {
        unsigned int o = f2b(acc[0] * inv) | ((unsigned int)f2b(acc[1] * inv) << 16);
        *(unsigned int*)(out + (size_t)i * D + lane * 2) = o;
    } else {
        uint2 o;
        o.x = f2b(acc[0] * inv) | ((unsigned int)f2b(acc[1] * inv) << 16);
        o.y = f2b(acc[2] * inv) | ((unsigned int)f2b(acc[3] * inv) << 16);
        *(uint2*)(out + (size_t)i * D + lane * 4) = o;
    }
}

// ---------------- MFMA dual GEMM: C = A1@B1t' + A2@B2t' + bias ----------------
template<bool BF16OUT>
__global__ void __launch_bounds__(256) k_mgemm(const unsigned short* __restrict__ A1,
                                               const unsigned short* __restrict__ Bt1, int K1,
                                               const unsigned short* __restrict__ A2,
                                               const unsigned short* __restrict__ Bt2, int K2,
                                               const float* __restrict__ bias,
                                               void* __restrict__ Cv, int M, int NN) {
    __shared__ unsigned short As[64 * 32];
    __shared__ unsigned short Bs[64 * 32];
    int tid = threadIdx.x;
    int w = tid >> 6, l = tid & 63;
    int mBase = blockIdx.x * 64, nBase = blockIdx.y * 64;
    f32x4 acc[4] = {};

    auto lds_off = [](int row, int col_bf16) -> int {
        return (row * 64 + col_bf16 * 2) ^ ((row & 7) << 4);
    };
    int srow = tid >> 2;
    int schunk = (tid & 3) << 3;
    int s_w_off = lds_off(srow, schunk);
    int kgrp = (l >> 4) << 3;
    int a_off = lds_off(w * 16 + (l & 15), kgrp);
    int b_off[4];
    #pragma unroll
    for (int c = 0; c < 4; ++c) b_off[c] = lds_off(c * 16 + (l & 15), kgrp);

    for (int pair = 0; pair < 2; ++pair) {
        const unsigned short* A  = pair ? A2 : A1;
        const unsigned short* Bt = pair ? Bt2 : Bt1;
        int K = pair ? K2 : K1;
        if (K == 0) break;
        for (int k0 = 0; k0 < K; k0 += 32) {
            u16x8 av = {};
            int arow = mBase + srow;
            if (arow < M) av = *(const u16x8*)&A[(size_t)arow * K + k0 + schunk];
            u16x8 bv = *(const u16x8*)&Bt[(size_t)(nBase + srow) * K + k0 + schunk];
            *(u16x8*)((char*)As + s_w_off) = av;
            *(u16x8*)((char*)Bs + s_w_off) = bv;
            __syncthreads();
            s16x8 a = *(const s16x8*)((const char*)As + a_off);
            #pragma unroll
            for (int c = 0; c < 4; ++c) {
                s16x8 bfr = *(const s16x8*)((const char*)Bs + b_off[c]);
                acc[c] = __builtin_amdgcn_mfma_f32_16x16x32_bf16(a, bfr, acc[c], 0, 0, 0);
            }
            __syncthreads();
        }
    }

    int colb = l & 15;
    int rbase = (l >> 4) << 2;
    #pragma unroll
    for (int c = 0; c < 4; ++c) {
        int gcol = nBase + c * 16 + colb;
        float bi = bias ? bias[gcol] : 0.f;
        #pragma unroll
        for (int r = 0; r < 4; ++r) {
            int grow = mBase + w * 16 + rbase + r;
            if (grow < M) {
                float v = acc[c][r] + bi;
                if constexpr (BF16OUT)
                    ((unsigned short*)Cv)[(size_t)grow * NN + gcol] = f2b(v);
                else
                    ((float*)Cv)[(size_t)grow * NN + gcol] = v;
            }
        }
    }
}

// ---------------- final fused GEMM: accout[col] += sum_rows relu(A@Btf + bg) ----------------
__global__ void __launch_bounds__(256) k_mgemm_mean(const unsigned short* __restrict__ A,
                                                    const unsigned short* __restrict__ Bt,
                                                    const float* __restrict__ bg,
                                                    float* __restrict__ accout, int M) {
    __shared__ unsigned short As[64 * 32];
    __shared__ unsigned short Bs[64 * 32];
    __shared__ float lds_cols[64];
    int tid = threadIdx.x;
    int w = tid >> 6, l = tid & 63;
    int mBase = blockIdx.x * 64;
    if (tid < 64) lds_cols[tid] = 0.f;
    f32x4 acc[4] = {};

    auto lds_off = [](int row, int col_bf16) -> int {
        return (row * 64 + col_bf16 * 2) ^ ((row & 7) << 4);
    };
    int srow = tid >> 2;
    int schunk = (tid & 3) << 3;
    int s_w_off = lds_off(srow, schunk);
    int kgrp = (l >> 4) << 3;
    int a_off = lds_off(w * 16 + (l & 15), kgrp);
    int b_off[4];
    #pragma unroll
    for (int c = 0; c < 4; ++c) b_off[c] = lds_off(c * 16 + (l & 15), kgrp);

    const int K = 256;
    for (int k0 = 0; k0 < K; k0 += 32) {
        u16x8 av = {};
        int arow = mBase + srow;
        if (arow < M) av = *(const u16x8*)&A[(size_t)arow * K + k0 + schunk];
        u16x8 bv = *(const u16x8*)&Bt[(size_t)srow * K + k0 + schunk];
        *(u16x8*)((char*)As + s_w_off) = av;
        *(u16x8*)((char*)Bs + s_w_off) = bv;
        __syncthreads();
        s16x8 a = *(const s16x8*)((const char*)As + a_off);
        #pragma unroll
        for (int c = 0; c < 4; ++c) {
            s16x8 bfr = *(const s16x8*)((const char*)Bs + b_off[c]);
            acc[c] = __builtin_amdgcn_mfma_f32_16x16x32_bf16(a, bfr, acc[c], 0, 0, 0);
        }
        __syncthreads();
    }

    int colb = l & 15;
    int rbase = (l >> 4) << 2;
    float csum[4];
    #pragma unroll
    for (int c = 0; c < 4; ++c) {
        int gcol = c * 16 + colb;
        float bi = bg[gcol];
        float sc = 0.f;
        #pragma unroll
        for (int r = 0; r < 4; ++r) {
            int grow = mBase + w * 16 + rbase + r;
            if (grow < M) sc += fmaxf(acc[c][r] + bi, 0.f);
        }
        sc += __shfl_xor(sc, 16);
        sc += __shfl_xor(sc, 32);
        csum[c] = sc;
    }
    if (l < 16) {
        #pragma unroll
        for (int c = 0; c < 4; ++c) atomicAdd(&lds_cols[c * 16 + l], csum[c]);
    }
    __syncthreads();
    if (tid < 64) atomicAdd(accout + tid, lds_cols[tid]);
}

// ---------------- BatchNorm ----------------
template<int C>
__global__ void k_colstats(const float* __restrict__ X, float* __restrict__ sum, float* __restrict__ sq) {
    constexpr int RPB = 256 / C;
    int tid = threadIdx.x;
    int c = tid % C;
    int r0 = blockIdx.x * RPB + tid / C;
    float s = 0.f, q = 0.f;
    for (int r = r0; r < N_NODES; r += gridDim.x * RPB) {
        float v = X[(size_t)r * C + c];
        s += v; q += v * v;
    }
    atomicAdd(&sum[c], s);
    atomicAdd(&sq[c], q);
}

template<int C>
__global__ void k_finstats(const float* __restrict__ sum, const float* __restrict__ sq,
                           const float* __restrict__ g, const float* __restrict__ be,
                           float* __restrict__ A, float* __restrict__ B) {
    int c = threadIdx.x;
    if (c < C) {
        float mu = sum[c] * (1.f / N_NODES);
        float var = sq[c] * (1.f / N_NODES) - mu * mu;
        float a = g[c] * rsqrtf(var + BN_EPS);
        A[c] = a;
        B[c] = be[c] - a * mu;
    }
}

template<int C>
__global__ void k_bnrelu_b(const float* __restrict__ X, const float* __restrict__ A,
                           const float* __restrict__ B, unsigned short* __restrict__ Y) {
    size_t total4 = (size_t)N_NODES * C / 4;
    for (size_t i = blockIdx.x * (size_t)blockDim.x + threadIdx.x; i < total4;
         i += (size_t)gridDim.x * blockDim.x) {
        int c4 = (int)((i * 4) % C);
        float4 x = ((const float4*)X)[i];
        float4 a = *(const float4*)&A[c4];
        float4 b = *(const float4*)&B[c4];
        float o0 = fmaxf(a.x * x.x + b.x, 0.f);
        float o1 = fmaxf(a.y * x.y + b.y, 0.f);
        float o2 = fmaxf(a.z * x.z + b.z, 0.f);
        float o3 = fmaxf(a.w * x.w + b.w, 0.f);
        uint2 o;
        o.x = f2b(o0) | ((unsigned int)f2b(o1) << 16);
        o.y = f2b(o2) | ((unsigned int)f2b(o3) << 16);
        ((uint2*)Y)[i] = o;
    }
}

// ---------------- SAGE-2 epilogue: h2 = mean_j z2[j] + b2l + r2_i ----------------
// zr: [N,128] bf16, cols 0-63 = z2 (=h1b@W2l), cols 64-127 = r2 (=h1b@W2r)
__global__ void __launch_bounds__(256) k_sage_add(const unsigned short* __restrict__ zr,
                                                  const int* __restrict__ rowptr,
                                                  const int* __restrict__ col,
                                                  const float* __restrict__ b2l,
                                                  float* __restrict__ h2) {
    int lane = threadIdx.x & 63;
    int i = (blockIdx.x << 2) + (threadIdx.x >> 6);
    if (i >= N_NODES) return;
    int b = rowptr[i], e = rowptr[i + 1];
    float acc = 0.f;
    for (int p = b; p < e; ++p) {
        int j = col[p];
        acc += b2f(zr[(size_t)j * 128 + lane]);
    }
    float inv = 1.f / fmaxf((float)(e - b), 1.f);
    float r = b2f(zr[(size_t)i * 128 + 64 + lane]);
    h2[(size_t)i * 64 + lane] = acc * inv + b2l[lane] + r;
}

// ---------------- GAT logits from h2b: att[i,h] = h2b_i . v_{src,dst}^h ----------------
__global__ void __launch_bounds__(256) k_attn2(const unsigned short* __restrict__ h2b,
                                               const float* __restrict__ vsrc,
                                               const float* __restrict__ vdst,
                                               float* __restrict__ att) {
    int lane = threadIdx.x & 63;
    int i = (blockIdx.x << 2) + (threadIdx.x >> 6);
    if (i >= N_NODES) return;
    float v = b2f(h2b[(size_t)i * 64 + lane]);
    #pragma unroll
    for (int h = 0; h < 4; ++h) {
        float s = v * vsrc[h * 64 + lane];
        float d = v * vdst[h * 64 + lane];
        #pragma unroll
        for (int o = 32; o; o >>= 1) {
            s += __shfl_xor(s, o);
            d += __shfl_xor(d, o);
        }
        if (lane == 0) { att[i * 8 + h] = s; att[i * 8 + 4 + h] = d; }
    }
}

// ---------------- GAT aggregate over h2b (L2-resident): per-head online softmax ----------------
// oagg[i, h*64+k] = sum_j alpha^h_ij h2[j,k]  (incl. self loop), normalized
__global__ void __launch_bounds__(256) k_gat2(const unsigned short* __restrict__ h2b,
                                              const float* __restrict__ att,
                                              const int* __restrict__ rowptr,
                                              const int* __restrict__ col,
                                              unsigned short* __restrict__ oagg) {
    int tid = threadIdx.x;
    int lane = tid & 63;
    int gw = (blockIdx.x << 2) + (tid >> 6);
    int stride = gridDim.x << 2;
    for (int i = gw; i < N_NODES; i += stride) {
        int b = rowptr[i], e = rowptr[i + 1];
        float4 ai = *(const float4*)(att + (size_t)i * 8);
        float4 ad = *(const float4*)(att + (size_t)i * 8 + 4);
        float hv = b2f(h2b[(size_t)i * 64 + lane]);
        float m[4], s[4], acc[4];
        m[0] = lrelu(ai.x + ad.x); m[1] = lrelu(ai.y + ad.y);
        m[2] = lrelu(ai.z + ad.z); m[3] = lrelu(ai.w + ad.w);
        #pragma unroll
        for (int h = 0; h < 4; ++h) { s[h] = 1.f; acc[h] = hv; }
        for (int p = b; p < e; ++p) {
            int j = col[p];
            float4 aj = *(const float4*)(att + (size_t)j * 8);
            float hj = b2f(h2b[(size_t)j * 64 + lane]);
            float e0 = lrelu(aj.x + ad.x);
            float e1 = lrelu(aj.y + ad.y);
            float e2 = lrelu(aj.z + ad.z);
            float e3 = lrelu(aj.w + ad.w);
            float mn, sc, wv;
            mn = fmaxf(m[0], e0); sc = __expf(m[0] - mn); wv = __expf(e0 - mn);
            s[0] = s[0] * sc + wv; acc[0] = acc[0] * sc + wv * hj; m[0] = mn;
            mn = fmaxf(m[1], e1); sc = __expf(m[1] - mn); wv = __expf(e1 - mn);
            s[1] = s[1] * sc + wv; acc[1] = acc[1] * sc + wv * hj; m[1] = mn;
            mn = fmaxf(m[2], e2); sc = __expf(m[2] - mn); wv = __expf(e2 - mn);
            s[2] = s[2] * sc + wv; acc[2] = acc[2] * sc + wv * hj; m[2] = mn;
            mn = fmaxf(m[3], e3); sc = __expf(m[3] - mn); wv = __expf(e3 - mn);
            s[3] = s[3] * sc + wv; acc[3] = acc[3] * sc + wv * hj; m[3] = mn;
        }
        #pragma unroll
        for (int h = 0; h < 4; ++h)
            oagg[(size_t)i * 256 + h * 64 + lane] = f2b(acc[h] / s[h]);
    }
}

__global__ void k_final(const float* __restrict__ accout, float* __restrict__ out) {
    int d = threadIdx.x;
    if (d < 64) out[d] = accout[d] * (1.f / N_NODES);
}

// ---------------- launch ----------------
extern "C" void kernel_launch(void* const* d_in, const int* in_sizes, int n_in,
                              void* d_out, int out_size, void* d_ws, size_t ws_size,
                              hipStream_t stream) {
    const float* x       = (const float*)d_in[0];
    const int*   ei      = (const int*)d_in[1];
    const float* W1l     = (const float*)d_in[2];
    const float* b1l     = (const float*)d_in[3];
    const float* W1r     = (const float*)d_in[4];
    const float* W2l     = (const float*)d_in[5];
    const float* b2l     = (const float*)d_in[6];
    const float* W2r     = (const float*)d_in[7];
    const float* g1      = (const float*)d_in[8];
    const float* be1     = (const float*)d_in[9];
    const float* g2      = (const float*)d_in[10];
    const float* be2     = (const float*)d_in[11];
    const float* Wg      = (const float*)d_in[12];
    const float* att_src = (const float*)d_in[13];
    const float* att_dst = (const float*)d_in[14];
    const float* bg      = (const float*)d_in[15];
    float* out = (float*)d_out;

    char* p = (char*)d_ws;
    auto alloc = [&](size_t bytes) -> char* {
        char* q = p;
        p += (bytes + 255) & ~(size_t)255;
        return q;
    };
    int*   cnt    = (int*)alloc((size_t)N_NODES * 4);
    float* stats  = (float*)alloc(1856 * 4);
    int*   rowptr = (int*)alloc((size_t)(N_NODES + 1) * 4);
    int*   bsums  = (int*)alloc(256 * 4);
    int*   col    = (int*)alloc((size_t)N_EDGES * 4);
    unsigned short* xb    = (unsigned short*)alloc((size_t)N_NODES * 128 * 2);  // 7.68MB
    unsigned short* agg1b = (unsigned short*)alloc((size_t)N_NODES * 128 * 2);  // 7.68MB (contiguous after xb)
    float* h1   = (float*)alloc((size_t)N_NODES * 256 * 4);                     // 30.72MB
    unsigned short* h1b = (unsigned short*)alloc((size_t)N_NODES * 256 * 2);    // 15.36MB
    float* att  = (float*)alloc((size_t)N_NODES * 8 * 4);
    unsigned short* w1lt = (unsigned short*)alloc(128 * 256 * 2);
    unsigned short* w1rt = (unsigned short*)alloc(128 * 256 * 2);
    unsigned short* w2lt = (unsigned short*)alloc(256 * 64 * 2);   // [w2lt|w2rt] contiguous = [128][256]
    unsigned short* w2rt = (unsigned short*)alloc(256 * 64 * 2);
    unsigned short* btf  = (unsigned short*)alloc(64 * 256 * 2);   // stacked Wg/4 for final GEMM

    // aliases (lifetimes verified):
    unsigned short* zr2b = agg1b;                                  // agg1b dead after mgemm1; dead before k_gat2
    float* h2  = (float*)((char*)h1 + 15360000);                   // h1 fp32 dead after bnrelu1
    unsigned short* h2b = (unsigned short*)((char*)h1 + 23040000);
    unsigned short* oagg = xb;                                     // xb+agg1b span 15.36MB, dead after sage_add

    float* sum1 = stats;        float* sq1 = stats + 256;
    float* A1s  = stats + 512;  float* B1s = stats + 768;
    float* sum2 = stats + 1024; float* sq2 = stats + 1088;
    float* A2s  = stats + 1152; float* B2s = stats + 1216;
    float* accout = stats + 1280;
    float* vsrc = stats + 1344; float* vdst = stats + 1600;

    const int* srcA = ei;
    const int* dstA = ei + N_EDGES;

    // CSR build
    k_init_zero<<<118, 256, 0, stream>>>(cnt, stats);
    k_count<<<(N_EDGES + 255) / 256, 256, 0, stream>>>(dstA, cnt);
    k_scan1<<<118, 256, 0, stream>>>(cnt, rowptr, bsums);
    k_scan2<<<1, 128, 0, stream>>>(bsums, 118);
    k_scan3<<<118, 256, 0, stream>>>(rowptr, bsums, cnt);
    k_fill<<<(N_EDGES + 255) / 256, 256, 0, stream>>>(srcA, dstA, rowptr, cnt, col);

    // conversions + GAT precomputes
    k_cvt_x<<<3750, 256, 0, stream>>>(x, xb);
    k_cvtW<<<448, 256, 0, stream>>>(W1l, W1r, W2l, W2r, Wg, w1lt, w1rt, w2lt, w2rt, btf);
    k_attvec<<<1, 256, 0, stream>>>(Wg, att_src, att_dst, vsrc, vdst);

    // SAGE layer 1 (aggregate-then-transform: 256B row gathers)
    k_sage_agg_b<128><<<(N_NODES + 3) / 4, 256, 0, stream>>>(xb, rowptr, col, agg1b);
    k_mgemm<false><<<dim3(469, 4), 256, 0, stream>>>(agg1b, w1lt, 128, xb, w1rt, 128, b1l, h1, N_NODES, 256);
    k_colstats<256><<<480, 256, 0, stream>>>(h1, sum1, sq1);
    k_finstats<256><<<1, 256, 0, stream>>>(sum1, sq1, g1, be1, A1s, B1s);
    k_bnrelu_b<256><<<1024, 256, 0, stream>>>(h1, A1s, B1s, h1b);

    // SAGE layer 2 (transform-then-aggregate: gather 128B rows from L2-resident zr2b)
    k_mgemm<true><<<dim3(469, 2), 256, 0, stream>>>(h1b, w2lt, 256, nullptr, nullptr, 0, nullptr, zr2b, N_NODES, 128);
    k_sage_add<<<(N_NODES + 3) / 4, 256, 0, stream>>>(zr2b, rowptr, col, b2l, h2);
    k_colstats<64><<<480, 256, 0, stream>>>(h2, sum2, sq2);
    k_finstats<64><<<1, 64, 0, stream>>>(sum2, sq2, g2, be2, A2s, B2s);
    k_bnrelu_b<64><<<512, 256, 0, stream>>>(h2, A2s, B2s, h2b);

    // GAT: logits and aggregation directly on h2b (3.84MB, L2-resident), Wg applied after
    k_attn2<<<(N_NODES + 3) / 4, 256, 0, stream>>>(h2b, vsrc, vdst, att);
    k_gat2<<<2048, 256, 0, stream>>>(h2b, att, rowptr, col, oagg);
    k_mgemm_mean<<<469, 256, 0, stream>>>(oagg, btf, bg, accout, N_NODES);
    k_final<<<1, 64, 0, stream>>>(accout, out);
}

// Round 7
// 273.746 us; speedup vs baseline: 2.0976x; 1.2256x over previous
//
#include <hip/hip_runtime.h>
#include <stdint.h>

#define N_NODES 30000
#define N_EDGES 300000
#define BN_EPS  1e-5f
#define NEG_SLOPE 0.2f

typedef __attribute__((ext_vector_type(8))) short          s16x8;
typedef __attribute__((ext_vector_type(8))) unsigned short u16x8;
typedef __attribute__((ext_vector_type(4))) float          f32x4;

__device__ __forceinline__ float b2f(unsigned int u) { return __uint_as_float(u << 16); }
__device__ __forceinline__ unsigned short f2b(float f) {
    unsigned int u = __float_as_uint(f);
    return (unsigned short)((u + 0x7fffu + ((u >> 16) & 1u)) >> 16);
}
__device__ __forceinline__ float lrelu(float a) { return fmaxf(a, NEG_SLOPE * a); }

// ---------------- prep: zero counters/stats/out + bf16 conversions + GAT vecs ----------------
__global__ void k_prep(int* __restrict__ cnt, float* __restrict__ stats, float* __restrict__ outz,
                       const float* __restrict__ x, unsigned short* __restrict__ xb,
                       const float* __restrict__ W1l, const float* __restrict__ W1r,
                       const float* __restrict__ W2l, const float* __restrict__ W2r,
                       const float* __restrict__ Wg,
                       unsigned short* __restrict__ t1l, unsigned short* __restrict__ t1r,
                       unsigned short* __restrict__ t2l, unsigned short* __restrict__ t2r,
                       unsigned short* __restrict__ btf,
                       const float* __restrict__ att_src, const float* __restrict__ att_dst,
                       float* __restrict__ vsrc, float* __restrict__ vdst) {
    int b = blockIdx.x, tid = threadIdx.x;
    if (b < 118) {
        int i = b * 256 + tid;
        if (i < N_NODES) cnt[i] = 0;
        if (i < 1344) stats[i] = 0.f;
        if (b == 0 && tid < 64) outz[tid] = 0.f;
    } else if (b < 1118) {
        for (int i = (b - 118) * 256 + tid; i < N_NODES * 128 / 4; i += 256000) {
            float4 v = ((const float4*)x)[i];
            unsigned int lo = f2b(v.x) | ((unsigned int)f2b(v.y) << 16);
            unsigned int hi = f2b(v.z) | ((unsigned int)f2b(v.w) << 16);
            ((uint2*)xb)[i] = make_uint2(lo, hi);
        }
    } else if (b < 1566) {
        int i = (b - 1118) * 256 + tid;
        if (i >= 114688) return;
        if (i >= 98304) {
            int j = i - 98304;
            int n = j >> 8, r = j & 255;
            int h = r >> 6, k = r & 63;
            btf[j] = f2b(Wg[k * 256 + h * 64 + n] * 0.25f);
            return;
        }
        const float* S; unsigned short* D; int K, NN, off;
        if (i < 32768)      { S = W1l; D = t1l; K = 128; NN = 256; off = 0; }
        else if (i < 65536) { S = W1r; D = t1r; K = 128; NN = 256; off = 32768; }
        else if (i < 81920) { S = W2l; D = t2l; K = 256; NN = 64;  off = 65536; }
        else                { S = W2r; D = t2r; K = 256; NN = 64;  off = 81920; }
        int j = i - off;
        int k = j / NN, n = j % NN;
        D[n * K + k] = f2b(S[j]);
    } else {
        // v_src[h,k] = sum_d Wg[k, h*64+d] * att_src[h,d]
        int h = tid >> 6, k = tid & 63;
        float s = 0.f, d = 0.f;
        for (int dd = 0; dd < 64; ++dd) {
            float w = Wg[k * 256 + h * 64 + dd];
            s += w * att_src[h * 64 + dd];
            d += w * att_dst[h * 64 + dd];
        }
        vsrc[h * 64 + k] = s;
        vdst[h * 64 + k] = d;
    }
}

// ---------------- CSR build ----------------
__global__ void k_count(const int* __restrict__ dst, int* __restrict__ cnt) {
    int e = blockIdx.x * 256 + threadIdx.x;
    if (e < N_EDGES) atomicAdd(&cnt[dst[e]], 1);
}

__global__ void k_scan1(const int* __restrict__ cnt, int* __restrict__ rowptr, int* __restrict__ bsums) {
    __shared__ int s[256];
    int tid = threadIdx.x;
    int idx = blockIdx.x * 256 + tid;
    int val = (idx < N_NODES) ? cnt[idx] : 0;
    s[tid] = val; __syncthreads();
    for (int o = 1; o < 256; o <<= 1) {
        int add = (tid >= o) ? s[tid - o] : 0;
        __syncthreads();
        s[tid] += add;
        __syncthreads();
    }
    if (idx < N_NODES) rowptr[idx] = s[tid] - val;
    if (tid == 255) bsums[blockIdx.x] = s[255];
}

__global__ void k_scan2(int* bsums, int nb) {
    __shared__ int s[128];
    int tid = threadIdx.x;
    int val = (tid < nb) ? bsums[tid] : 0;
    s[tid] = val; __syncthreads();
    for (int o = 1; o < 128; o <<= 1) {
        int add = (tid >= o) ? s[tid - o] : 0;
        __syncthreads();
        s[tid] += add;
        __syncthreads();
    }
    if (tid < nb) bsums[tid] = s[tid] - val;
}

__global__ void k_scan3(int* __restrict__ rowptr, const int* __restrict__ bsums, int* __restrict__ cnt) {
    int idx = blockIdx.x * 256 + threadIdx.x;
    if (idx < N_NODES) { rowptr[idx] += bsums[idx >> 8]; cnt[idx] = 0; }
    if (idx == 0) rowptr[N_NODES] = N_EDGES;
}

__global__ void k_fill(const int* __restrict__ srcA, const int* __restrict__ dstA,
                       const int* __restrict__ rowptr, int* __restrict__ cnt, int* __restrict__ col) {
    int e = blockIdx.x * 256 + threadIdx.x;
    if (e < N_EDGES) {
        int d = dstA[e];
        int pos = rowptr[d] + atomicAdd(&cnt[d], 1);
        col[pos] = srcA[e];
    }
}

// ---------------- SAGE mean aggregation (bf16, fp32 accum) ----------------
template<int D>
__global__ void __launch_bounds__(256) k_sage_agg_b(const unsigned short* __restrict__ X,
                                                    const int* __restrict__ rowptr,
                                                    const int* __restrict__ col,
                                                    unsigned short* __restrict__ out) {
    constexpr int V = D / 64;
    int lane = threadIdx.x & 63;
    int i = (blockIdx.x << 2) + (threadIdx.x >> 6);
    if (i >= N_NODES) return;
    int b = rowptr[i], e = rowptr[i + 1];
    float acc[V] = {};
    for (int p = b; p < e; ++p) {
        int j = col[p];
        const unsigned short* r = X + (size_t)j * D + lane * V;
        if constexpr (V == 2) {
            unsigned int v = *(const unsigned int*)r;
            acc[0] += b2f(v & 0xffffu); acc[1] += b2f(v >> 16);
        } else {
            uint2 v = *(const uint2*)r;
            acc[0] += b2f(v.x & 0xffffu); acc[1] += b2f(v.x >> 16);
            acc[2] += b2f(v.y & 0xffffu); acc[3] += b2f(v.y >> 16);
        }
    }
    float inv = 1.f / fmaxf((float)(e - b), 1.f);
    if constexpr (V == 2) {
        unsigned int o = f2b(acc[0] * inv) | ((unsigned int)f2b(acc[1] * inv) << 16);
        *(unsigned int*)(out + (size_t)i * D + lane * 2) = o;
    } else {
        uint2 o;
        o.x = f2b(acc[0] * inv) | ((unsigned int)f2b(acc[1] * inv) << 16);
        o.y = f2b(acc[2] * inv) | ((unsigned int)f2b(acc[3] * inv) << 16);
        *(uint2*)(out + (size_t)i * D + lane * 4) = o;
    }
}

// ---------------- MFMA dual GEMM with optional fused BN-on-A and column stats ----------------
// A: [M,K] bf16 row-major; Bt: [NN,K] bf16; C: [M,NN]
template<bool BF16OUT, bool BN_A, bool STATS>
__global__ void __launch_bounds__(256) k_mgemm(const unsigned short* __restrict__ A1,
                                               const unsigned short* __restrict__ Bt1, int K1,
                                               const unsigned short* __restrict__ A2,
                                               const unsigned short* __restrict__ Bt2, int K2,
                                               const float* __restrict__ bias,
                                               void* __restrict__ Cv, int M, int NN,
                                               const float* __restrict__ bnA,
                                               const float* __restrict__ bnB,
                                               float* __restrict__ stS, float* __restrict__ stQ) {
    __shared__ unsigned short As[64 * 32];
    __shared__ unsigned short Bs[64 * 32];
    int tid = threadIdx.x;
    int w = tid >> 6, l = tid & 63;
    int mBase = blockIdx.x * 64, nBase = blockIdx.y * 64;
    f32x4 acc[4] = {};

    auto lds_off = [](int row, int col_bf16) -> int {
        return (row * 64 + col_bf16 * 2) ^ ((row & 7) << 4);
    };
    int srow = tid >> 2;
    int schunk = (tid & 3) << 3;
    int s_w_off = lds_off(srow, schunk);
    int kgrp = (l >> 4) << 3;
    int a_off = lds_off(w * 16 + (l & 15), kgrp);
    int b_off[4];
    #pragma unroll
    for (int c = 0; c < 4; ++c) b_off[c] = lds_off(c * 16 + (l & 15), kgrp);

    for (int pair = 0; pair < 2; ++pair) {
        const unsigned short* A  = pair ? A2 : A1;
        const unsigned short* Bt = pair ? Bt2 : Bt1;
        int K = pair ? K2 : K1;
        if (K == 0) break;
        for (int k0 = 0; k0 < K; k0 += 32) {
            u16x8 av = {};
            int arow = mBase + srow;
            if (arow < M) {
                av = *(const u16x8*)&A[(size_t)arow * K + k0 + schunk];
                if constexpr (BN_A) {
                    const float* pa = &bnA[k0 + schunk];
                    const float* pb = &bnB[k0 + schunk];
                    #pragma unroll
                    for (int e2 = 0; e2 < 8; ++e2) {
                        float f = fmaxf(b2f(av[e2]) * pa[e2] + pb[e2], 0.f);
                        av[e2] = f2b(f);
                    }
                }
            }
            u16x8 bv = *(const u16x8*)&Bt[(size_t)(nBase + srow) * K + k0 + schunk];
            *(u16x8*)((char*)As + s_w_off) = av;
            *(u16x8*)((char*)Bs + s_w_off) = bv;
            __syncthreads();
            s16x8 a = *(const s16x8*)((const char*)As + a_off);
            #pragma unroll
            for (int c = 0; c < 4; ++c) {
                s16x8 bfr = *(const s16x8*)((const char*)Bs + b_off[c]);
                acc[c] = __builtin_amdgcn_mfma_f32_16x16x32_bf16(a, bfr, acc[c], 0, 0, 0);
            }
            __syncthreads();
        }
    }

    float* lst = (float*)As;  // LDS free after last barrier; 128 floats for stats
    if constexpr (STATS) {
        if (tid < 128) lst[tid] = 0.f;
        __syncthreads();
    }
    int colb = l & 15;
    int rbase = (l >> 4) << 2;
    #pragma unroll
    for (int c = 0; c < 4; ++c) {
        int gcol = nBase + c * 16 + colb;
        float bi = bias ? bias[gcol] : 0.f;
        float s_ = 0.f, q_ = 0.f;
        #pragma unroll
        for (int r = 0; r < 4; ++r) {
            int grow = mBase + w * 16 + rbase + r;
            if (grow < M) {
                float v = acc[c][r] + bi;
                if constexpr (BF16OUT)
                    ((unsigned short*)Cv)[(size_t)grow * NN + gcol] = f2b(v);
                else
                    ((float*)Cv)[(size_t)grow * NN + gcol] = v;
                if constexpr (STATS) { s_ += v; q_ += v * v; }
            }
        }
        if constexpr (STATS) {
            s_ += __shfl_xor(s_, 16); s_ += __shfl_xor(s_, 32);
            q_ += __shfl_xor(q_, 16); q_ += __shfl_xor(q_, 32);
            if (l < 16) {
                atomicAdd(&lst[c * 16 + l], s_);
                atomicAdd(&lst[64 + c * 16 + l], q_);
            }
        }
    }
    if constexpr (STATS) {
        __syncthreads();
        if (tid < 64) {
            atomicAdd(&stS[nBase + tid], lst[tid]);
            atomicAdd(&stQ[nBase + tid], lst[64 + tid]);
        }
    }
}

// ---------------- final fused GEMM: out[col] += (1/N) * sum_rows relu(A@Btf + bg) ----------------
__global__ void __launch_bounds__(256) k_mgemm_mean(const unsigned short* __restrict__ A,
                                                    const unsigned short* __restrict__ Bt,
                                                    const float* __restrict__ bg,
                                                    float* __restrict__ out, int M) {
    __shared__ unsigned short As[64 * 32];
    __shared__ unsigned short Bs[64 * 32];
    __shared__ float lds_cols[64];
    int tid = threadIdx.x;
    int w = tid >> 6, l = tid & 63;
    int mBase = blockIdx.x * 64;
    if (tid < 64) lds_cols[tid] = 0.f;
    f32x4 acc[4] = {};

    auto lds_off = [](int row, int col_bf16) -> int {
        return (row * 64 + col_bf16 * 2) ^ ((row & 7) << 4);
    };
    int srow = tid >> 2;
    int schunk = (tid & 3) << 3;
    int s_w_off = lds_off(srow, schunk);
    int kgrp = (l >> 4) << 3;
    int a_off = lds_off(w * 16 + (l & 15), kgrp);
    int b_off[4];
    #pragma unroll
    for (int c = 0; c < 4; ++c) b_off[c] = lds_off(c * 16 + (l & 15), kgrp);

    const int K = 256;
    for (int k0 = 0; k0 < K; k0 += 32) {
        u16x8 av = {};
        int arow = mBase + srow;
        if (arow < M) av = *(const u16x8*)&A[(size_t)arow * K + k0 + schunk];
        u16x8 bv = *(const u16x8*)&Bt[(size_t)srow * K + k0 + schunk];
        *(u16x8*)((char*)As + s_w_off) = av;
        *(u16x8*)((char*)Bs + s_w_off) = bv;
        __syncthreads();
        s16x8 a = *(const s16x8*)((const char*)As + a_off);
        #pragma unroll
        for (int c = 0; c < 4; ++c) {
            s16x8 bfr = *(const s16x8*)((const char*)Bs + b_off[c]);
            acc[c] = __builtin_amdgcn_mfma_f32_16x16x32_bf16(a, bfr, acc[c], 0, 0, 0);
        }
        __syncthreads();
    }

    int colb = l & 15;
    int rbase = (l >> 4) << 2;
    #pragma unroll
    for (int c = 0; c < 4; ++c) {
        int gcol = c * 16 + colb;
        float bi = bg[gcol];
        float sc = 0.f;
        #pragma unroll
        for (int r = 0; r < 4; ++r) {
            int grow = mBase + w * 16 + rbase + r;
            if (grow < M) sc += fmaxf(acc[c][r] + bi, 0.f);
        }
        sc += __shfl_xor(sc, 16);
        sc += __shfl_xor(sc, 32);
        if (l < 16) atomicAdd(&lds_cols[c * 16 + l], sc);
    }
    __syncthreads();
    if (tid < 64) atomicAdd(out + tid, lds_cols[tid] * (1.f / N_NODES));
}

// ---------------- finalize BN coefficients ----------------
template<int C>
__global__ void k_finstats(const float* __restrict__ sum, const float* __restrict__ sq,
                           const float* __restrict__ g, const float* __restrict__ be,
                           float* __restrict__ A, float* __restrict__ B) {
    int c = threadIdx.x;
    if (c < C) {
        float mu = sum[c] * (1.f / N_NODES);
        float var = sq[c] * (1.f / N_NODES) - mu * mu;
        float a = g[c] * rsqrtf(var + BN_EPS);
        A[c] = a;
        B[c] = be[c] - a * mu;
    }
}

// ---------------- SAGE-2 epilogue: h2 = mean_j z2[j] + b2l + r2_i, fused column stats ----------------
__global__ void __launch_bounds__(256) k_sage_add(const unsigned short* __restrict__ zr,
                                                  const int* __restrict__ rowptr,
                                                  const int* __restrict__ col,
                                                  const float* __restrict__ b2l,
                                                  float* __restrict__ h2,
                                                  float* __restrict__ stS, float* __restrict__ stQ) {
    __shared__ float ls[128];
    int tid = threadIdx.x;
    if (tid < 128) ls[tid] = 0.f;
    __syncthreads();
    int lane = tid & 63;
    int wid = tid >> 6;
    float bl = b2l[lane];
    float s_ = 0.f, q_ = 0.f;
    for (int i = blockIdx.x * 4 + wid; i < N_NODES; i += gridDim.x * 4) {
        int b = rowptr[i], e = rowptr[i + 1];
        float acc = 0.f;
        for (int p = b; p < e; ++p) {
            int j = col[p];
            acc += b2f(zr[(size_t)j * 128 + lane]);
        }
        float inv = 1.f / fmaxf((float)(e - b), 1.f);
        float v = acc * inv + bl + b2f(zr[(size_t)i * 128 + 64 + lane]);
        h2[(size_t)i * 64 + lane] = v;
        s_ += v; q_ += v * v;
    }
    atomicAdd(&ls[lane], s_);
    atomicAdd(&ls[64 + lane], q_);
    __syncthreads();
    if (tid < 64) {
        atomicAdd(&stS[tid], ls[tid]);
        atomicAdd(&stQ[tid], ls[64 + tid]);
    }
}

// ---------------- attn2: fused BN+relu+cast of h2 -> h2b, plus GAT logits ----------------
__global__ void __launch_bounds__(256) k_attn2(const float* __restrict__ h2,
                                               const float* __restrict__ A2s,
                                               const float* __restrict__ B2s,
                                               const float* __restrict__ vsrc,
                                               const float* __restrict__ vdst,
                                               unsigned short* __restrict__ h2b,
                                               float* __restrict__ att) {
    int tid = threadIdx.x;
    int lane = tid & 63;
    int wid = tid >> 6;
    float a2 = A2s[lane], b2 = B2s[lane];
    float vs0 = vsrc[lane], vs1 = vsrc[64 + lane], vs2 = vsrc[128 + lane], vs3 = vsrc[192 + lane];
    float vd0 = vdst[lane], vd1 = vdst[64 + lane], vd2 = vdst[128 + lane], vd3 = vdst[192 + lane];
    for (int i = blockIdx.x * 4 + wid; i < N_NODES; i += gridDim.x * 4) {
        float v = fmaxf(h2[(size_t)i * 64 + lane] * a2 + b2, 0.f);
        h2b[(size_t)i * 64 + lane] = f2b(v);
        float s0 = v * vs0, s1 = v * vs1, s2 = v * vs2, s3 = v * vs3;
        float d0 = v * vd0, d1 = v * vd1, d2 = v * vd2, d3 = v * vd3;
        #pragma unroll
        for (int o = 32; o; o >>= 1) {
            s0 += __shfl_xor(s0, o); s1 += __shfl_xor(s1, o);
            s2 += __shfl_xor(s2, o); s3 += __shfl_xor(s3, o);
            d0 += __shfl_xor(d0, o); d1 += __shfl_xor(d1, o);
            d2 += __shfl_xor(d2, o); d3 += __shfl_xor(d3, o);
        }
        if (lane == 0) {
            float4* ap = (float4*)(att + (size_t)i * 8);
            ap[0] = make_float4(s0, s1, s2, s3);
            ap[1] = make_float4(d0, d1, d2, d3);
        }
    }
}

// ---------------- GAT aggregate: plain-exp softmax (logits provably small) ----------------
__global__ void __launch_bounds__(256) k_gat2(const unsigned short* __restrict__ h2b,
                                              const float* __restrict__ att,
                                              const int* __restrict__ rowptr,
                                              const int* __restrict__ col,
                                              unsigned short* __restrict__ oagg) {
    int tid = threadIdx.x;
    int lane = tid & 63;
    int gw = (blockIdx.x << 2) + (tid >> 6);
    int stride = gridDim.x << 2;
    for (int i = gw; i < N_NODES; i += stride) {
        int b = rowptr[i], e = rowptr[i + 1];
        float4 ai = *(const float4*)(att + (size_t)i * 8);
        float4 ad = *(const float4*)(att + (size_t)i * 8 + 4);
        float hv = b2f(h2b[(size_t)i * 64 + lane]);
        float w0 = __expf(lrelu(ai.x + ad.x));
        float w1 = __expf(lrelu(ai.y + ad.y));
        float w2 = __expf(lrelu(ai.z + ad.z));
        float w3 = __expf(lrelu(ai.w + ad.w));
        float s0 = w0, s1 = w1, s2 = w2, s3 = w3;
        float a0 = w0 * hv, a1 = w1 * hv, a2 = w2 * hv, a3 = w3 * hv;
        for (int p = b; p < e; ++p) {
            int j = col[p];
            float4 aj = *(const float4*)(att + (size_t)j * 8);
            float hj = b2f(h2b[(size_t)j * 64 + lane]);
            float e0 = __expf(lrelu(aj.x + ad.x));
            float e1 = __expf(lrelu(aj.y + ad.y));
            float e2 = __expf(lrelu(aj.z + ad.z));
            float e3 = __expf(lrelu(aj.w + ad.w));
            s0 += e0; a0 = fmaf(e0, hj, a0);
            s1 += e1; a1 = fmaf(e1, hj, a1);
            s2 += e2; a2 = fmaf(e2, hj, a2);
            s3 += e3; a3 = fmaf(e3, hj, a3);
        }
        unsigned short* op = oagg + (size_t)i * 256 + lane;
        op[0]   = f2b(a0 / s0);
        op[64]  = f2b(a1 / s1);
        op[128] = f2b(a2 / s2);
        op[192] = f2b(a3 / s3);
    }
}

// ---------------- launch ----------------
extern "C" void kernel_launch(void* const* d_in, const int* in_sizes, int n_in,
                              void* d_out, int out_size, void* d_ws, size_t ws_size,
                              hipStream_t stream) {
    const float* x       = (const float*)d_in[0];
    const int*   ei      = (const int*)d_in[1];
    const float* W1l     = (const float*)d_in[2];
    const float* b1l     = (const float*)d_in[3];
    const float* W1r     = (const float*)d_in[4];
    const float* W2l     = (const float*)d_in[5];
    const float* b2l     = (const float*)d_in[6];
    const float* W2r     = (const float*)d_in[7];
    const float* g1      = (const float*)d_in[8];
    const float* be1     = (const float*)d_in[9];
    const float* g2      = (const float*)d_in[10];
    const float* be2     = (const float*)d_in[11];
    const float* Wg      = (const float*)d_in[12];
    const float* att_src = (const float*)d_in[13];
    const float* att_dst = (const float*)d_in[14];
    const float* bg      = (const float*)d_in[15];
    float* out = (float*)d_out;

    char* p = (char*)d_ws;
    auto alloc = [&](size_t bytes) -> char* {
        char* q = p;
        p += (bytes + 255) & ~(size_t)255;
        return q;
    };
    int*   cnt    = (int*)alloc((size_t)N_NODES * 4);
    float* stats  = (float*)alloc(1856 * 4);
    int*   rowptr = (int*)alloc((size_t)(N_NODES + 1) * 4);
    int*   bsums  = (int*)alloc(256 * 4);
    int*   col    = (int*)alloc((size_t)N_EDGES * 4);
    unsigned short* xb    = (unsigned short*)alloc((size_t)N_NODES * 128 * 2);  // 7.68MB
    unsigned short* agg1b = (unsigned short*)alloc((size_t)N_NODES * 128 * 2);  // 7.68MB, contiguous after xb
    unsigned short* h1b = (unsigned short*)alloc((size_t)N_NODES * 256 * 2);    // 15.36MB
    float* h2   = (float*)alloc((size_t)N_NODES * 64 * 4);                      // 7.68MB
    unsigned short* h2b = (unsigned short*)alloc((size_t)N_NODES * 64 * 2);     // 3.84MB
    float* att  = (float*)alloc((size_t)N_NODES * 8 * 4);
    unsigned short* w1lt = (unsigned short*)alloc(128 * 256 * 2);
    unsigned short* w1rt = (unsigned short*)alloc(128 * 256 * 2);
    unsigned short* w2lt = (unsigned short*)alloc(256 * 64 * 2);   // [w2lt|w2rt] contiguous [128][256]
    unsigned short* w2rt = (unsigned short*)alloc(256 * 64 * 2);
    unsigned short* btf  = (unsigned short*)alloc(64 * 256 * 2);

    // aliases (lifetimes): zr2b=agg1b dead after k_sage_add; oagg spans xb+agg1b (both dead by k_gat2)
    unsigned short* zr2b = agg1b;
    unsigned short* oagg = xb;

    float* sum1 = stats;        float* sq1 = stats + 256;
    float* A1s  = stats + 512;  float* B1s = stats + 768;
    float* sum2 = stats + 1024; float* sq2 = stats + 1088;
    float* A2s  = stats + 1152; float* B2s = stats + 1216;
    float* vsrc = stats + 1344; float* vdst = stats + 1600;

    const int* srcA = ei;
    const int* dstA = ei + N_EDGES;

    // prep (zero cnt/stats/out, cvt x, cvt+transpose weights, attention vecs)
    k_prep<<<1567, 256, 0, stream>>>(cnt, stats, out, x, xb, W1l, W1r, W2l, W2r, Wg,
                                     w1lt, w1rt, w2lt, w2rt, btf, att_src, att_dst, vsrc, vdst);
    // CSR build
    k_count<<<1172, 256, 0, stream>>>(dstA, cnt);
    k_scan1<<<118, 256, 0, stream>>>(cnt, rowptr, bsums);
    k_scan2<<<1, 128, 0, stream>>>(bsums, 118);
    k_scan3<<<118, 256, 0, stream>>>(rowptr, bsums, cnt);
    k_fill<<<1172, 256, 0, stream>>>(srcA, dstA, rowptr, cnt, col);

    // SAGE layer 1: aggregate -> dual GEMM (bf16 out + fused column stats) -> BN coeffs
    k_sage_agg_b<128><<<7500, 256, 0, stream>>>(xb, rowptr, col, agg1b);
    k_mgemm<true, false, true><<<dim3(469, 4), 256, 0, stream>>>(
        agg1b, w1lt, 128, xb, w1rt, 128, b1l, h1b, N_NODES, 256, nullptr, nullptr, sum1, sq1);
    k_finstats<256><<<1, 256, 0, stream>>>(sum1, sq1, g1, be1, A1s, B1s);

    // SAGE layer 2: GEMM with fused BN+relu on A -> gather-add (fused stats) -> BN coeffs
    k_mgemm<true, true, false><<<dim3(469, 2), 256, 0, stream>>>(
        h1b, w2lt, 256, nullptr, nullptr, 0, nullptr, zr2b, N_NODES, 128, A1s, B1s, nullptr, nullptr);
    k_sage_add<<<940, 256, 0, stream>>>(zr2b, rowptr, col, b2l, h2, sum2, sq2);
    k_finstats<64><<<1, 64, 0, stream>>>(sum2, sq2, g2, be2, A2s, B2s);

    // GAT: BN+relu+logits fused -> plain-exp softmax aggregate -> projection+mean GEMM into out
    k_attn2<<<1875, 256, 0, stream>>>(h2, A2s, B2s, vsrc, vdst, h2b, att);
    k_gat2<<<2048, 256, 0, stream>>>(h2b, att, rowptr, col, oagg);
    k_mgemm_mean<<<469, 256, 0, stream>>>(oagg, btf, bg, out, N_NODES);
}

// Round 8
// 245.516 us; speedup vs baseline: 2.3388x; 1.1150x over previous
//
#include <hip/hip_runtime.h>
#include <stdint.h>

#define N_NODES 30000
#define N_EDGES 300000
#define BN_EPS  1e-5f
#define NEG_SLOPE 0.2f

typedef __attribute__((ext_vector_type(8))) short          s16x8;
typedef __attribute__((ext_vector_type(8))) unsigned short u16x8;
typedef __attribute__((ext_vector_type(4))) float          f32x4;

__device__ __forceinline__ float b2f(unsigned int u) { return __uint_as_float(u << 16); }
__device__ __forceinline__ unsigned short f2b(float f) {
    unsigned int u = __float_as_uint(f);
    return (unsigned short)((u + 0x7fffu + ((u >> 16) & 1u)) >> 16);
}
__device__ __forceinline__ float lrelu(float a) { return fmaxf(a, NEG_SLOPE * a); }

// ---------------- prep: zero counters/stats/out + bf16 conversions + GAT vecs ----------------
__global__ void k_prep(int* __restrict__ cnt, float* __restrict__ stats, float* __restrict__ outz,
                       const float* __restrict__ x, unsigned short* __restrict__ xb,
                       const float* __restrict__ W1l, const float* __restrict__ W1r,
                       const float* __restrict__ W2l, const float* __restrict__ W2r,
                       const float* __restrict__ Wg,
                       unsigned short* __restrict__ t1l, unsigned short* __restrict__ t1r,
                       unsigned short* __restrict__ t2l, unsigned short* __restrict__ t2r,
                       unsigned short* __restrict__ btf,
                       const float* __restrict__ att_src, const float* __restrict__ att_dst,
                       float* __restrict__ vsrc, float* __restrict__ vdst) {
    int b = blockIdx.x, tid = threadIdx.x;
    if (b < 118) {
        int i = b * 256 + tid;
        if (i < N_NODES) cnt[i] = 0;
        if (i < 1344) stats[i] = 0.f;
        if (b == 0 && tid < 64) outz[tid] = 0.f;
    } else if (b < 1118) {
        for (int i = (b - 118) * 256 + tid; i < N_NODES * 128 / 4; i += 256000) {
            float4 v = ((const float4*)x)[i];
            unsigned int lo = f2b(v.x) | ((unsigned int)f2b(v.y) << 16);
            unsigned int hi = f2b(v.z) | ((unsigned int)f2b(v.w) << 16);
            ((uint2*)xb)[i] = make_uint2(lo, hi);
        }
    } else if (b < 1566) {
        int i = (b - 1118) * 256 + tid;
        if (i >= 114688) return;
        if (i >= 98304) {
            int j = i - 98304;
            int n = j >> 8, r = j & 255;
            int h = r >> 6, k = r & 63;
            btf[j] = f2b(Wg[k * 256 + h * 64 + n] * 0.25f);
            return;
        }
        const float* S; unsigned short* D; int K, NN, off;
        if (i < 32768)      { S = W1l; D = t1l; K = 128; NN = 256; off = 0; }
        else if (i < 65536) { S = W1r; D = t1r; K = 128; NN = 256; off = 32768; }
        else if (i < 81920) { S = W2l; D = t2l; K = 256; NN = 64;  off = 65536; }
        else                { S = W2r; D = t2r; K = 256; NN = 64;  off = 81920; }
        int j = i - off;
        int k = j / NN, n = j % NN;
        D[n * K + k] = f2b(S[j]);
    } else {
        // v_src[h,k] = sum_d Wg[k, h*64+d] * att_src[h,d]
        int h = tid >> 6, k = tid & 63;
        float s = 0.f, d = 0.f;
        for (int dd = 0; dd < 64; ++dd) {
            float w = Wg[k * 256 + h * 64 + dd];
            s += w * att_src[h * 64 + dd];
            d += w * att_dst[h * 64 + dd];
        }
        vsrc[h * 64 + k] = s;
        vdst[h * 64 + k] = d;
    }
}

// ---------------- CSR build ----------------
__global__ void k_count(const int* __restrict__ dst, int* __restrict__ cnt) {
    int e = blockIdx.x * 256 + threadIdx.x;
    if (e < N_EDGES) atomicAdd(&cnt[dst[e]], 1);
}

__global__ void k_scan1(const int* __restrict__ cnt, int* __restrict__ rowptr, int* __restrict__ bsums) {
    __shared__ int s[256];
    int tid = threadIdx.x;
    int idx = blockIdx.x * 256 + tid;
    int val = (idx < N_NODES) ? cnt[idx] : 0;
    s[tid] = val; __syncthreads();
    for (int o = 1; o < 256; o <<= 1) {
        int add = (tid >= o) ? s[tid - o] : 0;
        __syncthreads();
        s[tid] += add;
        __syncthreads();
    }
    if (idx < N_NODES) rowptr[idx] = s[tid] - val;
    if (tid == 255) bsums[blockIdx.x] = s[255];
}

__global__ void k_scan2(int* bsums, int nb) {
    __shared__ int s[128];
    int tid = threadIdx.x;
    int val = (tid < nb) ? bsums[tid] : 0;
    s[tid] = val; __syncthreads();
    for (int o = 1; o < 128; o <<= 1) {
        int add = (tid >= o) ? s[tid - o] : 0;
        __syncthreads();
        s[tid] += add;
        __syncthreads();
    }
    if (tid < nb) bsums[tid] = s[tid] - val;
}

__global__ void k_scan3(int* __restrict__ rowptr, const int* __restrict__ bsums, int* __restrict__ cnt) {
    int idx = blockIdx.x * 256 + threadIdx.x;
    if (idx < N_NODES) { rowptr[idx] += bsums[idx >> 8]; cnt[idx] = 0; }
    if (idx == 0) rowptr[N_NODES] = N_EDGES;
}

__global__ void k_fill(const int* __restrict__ srcA, const int* __restrict__ dstA,
                       const int* __restrict__ rowptr, int* __restrict__ cnt, int* __restrict__ col) {
    int e = blockIdx.x * 256 + threadIdx.x;
    if (e < N_EDGES) {
        int d = dstA[e];
        int pos = rowptr[d] + atomicAdd(&cnt[d], 1);
        col[pos] = srcA[e];
    }
}

// ---------------- SAGE-1 mean aggregation (bf16, fp32 accum, 4-way MLP unroll) ----------------
__global__ void __launch_bounds__(256) k_sage_agg_b(const unsigned short* __restrict__ X,
                                                    const int* __restrict__ rowptr,
                                                    const int* __restrict__ col,
                                                    unsigned short* __restrict__ out) {
    int lane = threadIdx.x & 63;
    int i = (blockIdx.x << 2) + (threadIdx.x >> 6);
    if (i >= N_NODES) return;
    int b = rowptr[i], e = rowptr[i + 1];
    float aA0 = 0.f, aA1 = 0.f, aB0 = 0.f, aB1 = 0.f;
    int p = b;
    for (; p + 4 <= e; p += 4) {
        int j0 = col[p], j1 = col[p + 1], j2 = col[p + 2], j3 = col[p + 3];
        unsigned int v0 = *(const unsigned int*)(X + (size_t)j0 * 128 + lane * 2);
        unsigned int v1 = *(const unsigned int*)(X + (size_t)j1 * 128 + lane * 2);
        unsigned int v2 = *(const unsigned int*)(X + (size_t)j2 * 128 + lane * 2);
        unsigned int v3 = *(const unsigned int*)(X + (size_t)j3 * 128 + lane * 2);
        aA0 += b2f(v0 & 0xffffu) + b2f(v2 & 0xffffu);
        aA1 += b2f(v0 >> 16) + b2f(v2 >> 16);
        aB0 += b2f(v1 & 0xffffu) + b2f(v3 & 0xffffu);
        aB1 += b2f(v1 >> 16) + b2f(v3 >> 16);
    }
    for (; p < e; ++p) {
        int j = col[p];
        unsigned int v = *(const unsigned int*)(X + (size_t)j * 128 + lane * 2);
        aA0 += b2f(v & 0xffffu);
        aA1 += b2f(v >> 16);
    }
    float inv = 1.f / fmaxf((float)(e - b), 1.f);
    float r0 = (aA0 + aB0) * inv, r1 = (aA1 + aB1) * inv;
    *(unsigned int*)(out + (size_t)i * 128 + lane * 2) = f2b(r0) | ((unsigned int)f2b(r1) << 16);
}

// ---------------- MFMA dual GEMM with optional fused BN-on-A / column stats / split-write ----------------
// A: [M,K] bf16 row-major; Bt: [NN,K] bf16; C: [M,NN]. If Cv2!=null (NN==128, bf16):
// cols 0-63 -> Cv[row*64+c], cols 64-127 -> Cv2[row*64+c-64].
template<bool BF16OUT, bool BN_A, bool STATS>
__global__ void __launch_bounds__(256) k_mgemm(const unsigned short* __restrict__ A1,
                                               const unsigned short* __restrict__ Bt1, int K1,
                                               const unsigned short* __restrict__ A2,
                                               const unsigned short* __restrict__ Bt2, int K2,
                                               const float* __restrict__ bias,
                                               void* __restrict__ Cv, unsigned short* __restrict__ Cv2,
                                               int M, int NN,
                                               const float* __restrict__ bnA,
                                               const float* __restrict__ bnB,
                                               float* __restrict__ stS, float* __restrict__ stQ) {
    __shared__ unsigned short As[64 * 32];
    __shared__ unsigned short Bs[64 * 32];
    int tid = threadIdx.x;
    int w = tid >> 6, l = tid & 63;
    int mBase = blockIdx.x * 64, nBase = blockIdx.y * 64;
    f32x4 acc[4] = {};

    auto lds_off = [](int row, int col_bf16) -> int {
        return (row * 64 + col_bf16 * 2) ^ ((row & 7) << 4);
    };
    int srow = tid >> 2;
    int schunk = (tid & 3) << 3;
    int s_w_off = lds_off(srow, schunk);
    int kgrp = (l >> 4) << 3;
    int a_off = lds_off(w * 16 + (l & 15), kgrp);
    int b_off[4];
    #pragma unroll
    for (int c = 0; c < 4; ++c) b_off[c] = lds_off(c * 16 + (l & 15), kgrp);

    for (int pair = 0; pair < 2; ++pair) {
        const unsigned short* A  = pair ? A2 : A1;
        const unsigned short* Bt = pair ? Bt2 : Bt1;
        int K = pair ? K2 : K1;
        if (K == 0) break;
        for (int k0 = 0; k0 < K; k0 += 32) {
            u16x8 av = {};
            int arow = mBase + srow;
            if (arow < M) {
                av = *(const u16x8*)&A[(size_t)arow * K + k0 + schunk];
                if constexpr (BN_A) {
                    const float* pa = &bnA[k0 + schunk];
                    const float* pb = &bnB[k0 + schunk];
                    #pragma unroll
                    for (int e2 = 0; e2 < 8; ++e2) {
                        float f = fmaxf(b2f(av[e2]) * pa[e2] + pb[e2], 0.f);
                        av[e2] = f2b(f);
                    }
                }
            }
            u16x8 bv = *(const u16x8*)&Bt[(size_t)(nBase + srow) * K + k0 + schunk];
            *(u16x8*)((char*)As + s_w_off) = av;
            *(u16x8*)((char*)Bs + s_w_off) = bv;
            __syncthreads();
            s16x8 a = *(const s16x8*)((const char*)As + a_off);
            #pragma unroll
            for (int c = 0; c < 4; ++c) {
                s16x8 bfr = *(const s16x8*)((const char*)Bs + b_off[c]);
                acc[c] = __builtin_amdgcn_mfma_f32_16x16x32_bf16(a, bfr, acc[c], 0, 0, 0);
            }
            __syncthreads();
        }
    }

    float* lst = (float*)As;  // LDS free after last barrier
    if constexpr (STATS) {
        if (tid < 128) lst[tid] = 0.f;
        __syncthreads();
    }
    int colb = l & 15;
    int rbase = (l >> 4) << 2;
    #pragma unroll
    for (int c = 0; c < 4; ++c) {
        int gcol = nBase + c * 16 + colb;
        float bi = bias ? bias[gcol] : 0.f;
        float s_ = 0.f, q_ = 0.f;
        #pragma unroll
        for (int r = 0; r < 4; ++r) {
            int grow = mBase + w * 16 + rbase + r;
            if (grow < M) {
                float v = acc[c][r] + bi;
                if constexpr (BF16OUT) {
                    unsigned short v16 = f2b(v);
                    if (Cv2) {
                        if (gcol < 64) ((unsigned short*)Cv)[(size_t)grow * 64 + gcol] = v16;
                        else           Cv2[(size_t)grow * 64 + gcol - 64] = v16;
                    } else {
                        ((unsigned short*)Cv)[(size_t)grow * NN + gcol] = v16;
                    }
                } else {
                    ((float*)Cv)[(size_t)grow * NN + gcol] = v;
                }
                if constexpr (STATS) { s_ += v; q_ += v * v; }
            }
        }
        if constexpr (STATS) {
            s_ += __shfl_xor(s_, 16); s_ += __shfl_xor(s_, 32);
            q_ += __shfl_xor(q_, 16); q_ += __shfl_xor(q_, 32);
            if (l < 16) {
                atomicAdd(&lst[c * 16 + l], s_);
                atomicAdd(&lst[64 + c * 16 + l], q_);
            }
        }
    }
    if constexpr (STATS) {
        __syncthreads();
        if (tid < 64) {
            atomicAdd(&stS[nBase + tid], lst[tid]);
            atomicAdd(&stQ[nBase + tid], lst[64 + tid]);
        }
    }
}

// ---------------- final fused GEMM: out[col] += (1/N) * sum_rows relu(A@Btf + bg) ----------------
__global__ void __launch_bounds__(256) k_mgemm_mean(const unsigned short* __restrict__ A,
                                                    const unsigned short* __restrict__ Bt,
                                                    const float* __restrict__ bg,
                                                    float* __restrict__ out, int M) {
    __shared__ unsigned short As[64 * 32];
    __shared__ unsigned short Bs[64 * 32];
    __shared__ float lds_cols[64];
    int tid = threadIdx.x;
    int w = tid >> 6, l = tid & 63;
    int mBase = blockIdx.x * 64;
    if (tid < 64) lds_cols[tid] = 0.f;
    f32x4 acc[4] = {};

    auto lds_off = [](int row, int col_bf16) -> int {
        return (row * 64 + col_bf16 * 2) ^ ((row & 7) << 4);
    };
    int srow = tid >> 2;
    int schunk = (tid & 3) << 3;
    int s_w_off = lds_off(srow, schunk);
    int kgrp = (l >> 4) << 3;
    int a_off = lds_off(w * 16 + (l & 15), kgrp);
    int b_off[4];
    #pragma unroll
    for (int c = 0; c < 4; ++c) b_off[c] = lds_off(c * 16 + (l & 15), kgrp);

    const int K = 256;
    for (int k0 = 0; k0 < K; k0 += 32) {
        u16x8 av = {};
        int arow = mBase + srow;
        if (arow < M) av = *(const u16x8*)&A[(size_t)arow * K + k0 + schunk];
        u16x8 bv = *(const u16x8*)&Bt[(size_t)srow * K + k0 + schunk];
        *(u16x8*)((char*)As + s_w_off) = av;
        *(u16x8*)((char*)Bs + s_w_off) = bv;
        __syncthreads();
        s16x8 a = *(const s16x8*)((const char*)As + a_off);
        #pragma unroll
        for (int c = 0; c < 4; ++c) {
            s16x8 bfr = *(const s16x8*)((const char*)Bs + b_off[c]);
            acc[c] = __builtin_amdgcn_mfma_f32_16x16x32_bf16(a, bfr, acc[c], 0, 0, 0);
        }
        __syncthreads();
    }

    int colb = l & 15;
    int rbase = (l >> 4) << 2;
    #pragma unroll
    for (int c = 0; c < 4; ++c) {
        int gcol = c * 16 + colb;
        float bi = bg[gcol];
        float sc = 0.f;
        #pragma unroll
        for (int r = 0; r < 4; ++r) {
            int grow = mBase + w * 16 + rbase + r;
            if (grow < M) sc += fmaxf(acc[c][r] + bi, 0.f);
        }
        sc += __shfl_xor(sc, 16);
        sc += __shfl_xor(sc, 32);
        if (l < 16) atomicAdd(&lds_cols[c * 16 + l], sc);
    }
    __syncthreads();
    if (tid < 64) atomicAdd(out + tid, lds_cols[tid] * (1.f / N_NODES));
}

// ---------------- finalize BN coefficients ----------------
template<int C>
__global__ void k_finstats(const float* __restrict__ sum, const float* __restrict__ sq,
                           const float* __restrict__ g, const float* __restrict__ be,
                           float* __restrict__ A, float* __restrict__ B) {
    int c = threadIdx.x;
    if (c < C) {
        float mu = sum[c] * (1.f / N_NODES);
        float var = sq[c] * (1.f / N_NODES) - mu * mu;
        float a = g[c] * rsqrtf(var + BN_EPS);
        A[c] = a;
        B[c] = be[c] - a * mu;
    }
}

// ---------------- SAGE-2 epilogue: h2 = mean_j z2[j] + b2l + r2_i, fused stats, 4-way MLP ----------------
__global__ void __launch_bounds__(256) k_sage_add(const unsigned short* __restrict__ z2,
                                                  const unsigned short* __restrict__ r2,
                                                  const int* __restrict__ rowptr,
                                                  const int* __restrict__ col,
                                                  const float* __restrict__ b2l,
                                                  float* __restrict__ h2,
                                                  float* __restrict__ stS, float* __restrict__ stQ) {
    __shared__ float ls[128];
    int tid = threadIdx.x;
    if (tid < 128) ls[tid] = 0.f;
    __syncthreads();
    int lane = tid & 63;
    int wid = tid >> 6;
    float bl = b2l[lane];
    float s_ = 0.f, q_ = 0.f;
    for (int i = blockIdx.x * 4 + wid; i < N_NODES; i += gridDim.x * 4) {
        int b = rowptr[i], e = rowptr[i + 1];
        float aA = 0.f, aB = 0.f;
        int p = b;
        for (; p + 4 <= e; p += 4) {
            int j0 = col[p], j1 = col[p + 1], j2 = col[p + 2], j3 = col[p + 3];
            float v0 = b2f(z2[(size_t)j0 * 64 + lane]);
            float v1 = b2f(z2[(size_t)j1 * 64 + lane]);
            float v2 = b2f(z2[(size_t)j2 * 64 + lane]);
            float v3 = b2f(z2[(size_t)j3 * 64 + lane]);
            aA += v0 + v2;
            aB += v1 + v3;
        }
        for (; p < e; ++p) aA += b2f(z2[(size_t)col[p] * 64 + lane]);
        float inv = 1.f / fmaxf((float)(e - b), 1.f);
        float v = (aA + aB) * inv + bl + b2f(r2[(size_t)i * 64 + lane]);
        h2[(size_t)i * 64 + lane] = v;
        s_ += v; q_ += v * v;
    }
    atomicAdd(&ls[lane], s_);
    atomicAdd(&ls[64 + lane], q_);
    __syncthreads();
    if (tid < 64) {
        atomicAdd(&stS[tid], ls[tid]);
        atomicAdd(&stQ[tid], ls[64 + tid]);
    }
}

// ---------------- attn2: fused BN+relu+cast of h2 -> h2b, plus GAT logits ----------------
__global__ void __launch_bounds__(256) k_attn2(const float* __restrict__ h2,
                                               const float* __restrict__ A2s,
                                               const float* __restrict__ B2s,
                                               const float* __restrict__ vsrc,
                                               const float* __restrict__ vdst,
                                               unsigned short* __restrict__ h2b,
                                               float* __restrict__ att) {
    int tid = threadIdx.x;
    int lane = tid & 63;
    int wid = tid >> 6;
    float a2 = A2s[lane], b2 = B2s[lane];
    float vs0 = vsrc[lane], vs1 = vsrc[64 + lane], vs2 = vsrc[128 + lane], vs3 = vsrc[192 + lane];
    float vd0 = vdst[lane], vd1 = vdst[64 + lane], vd2 = vdst[128 + lane], vd3 = vdst[192 + lane];
    for (int i = blockIdx.x * 4 + wid; i < N_NODES; i += gridDim.x * 4) {
        float v = fmaxf(h2[(size_t)i * 64 + lane] * a2 + b2, 0.f);
        h2b[(size_t)i * 64 + lane] = f2b(v);
        float s0 = v * vs0, s1 = v * vs1, s2 = v * vs2, s3 = v * vs3;
        float d0 = v * vd0, d1 = v * vd1, d2 = v * vd2, d3 = v * vd3;
        #pragma unroll
        for (int o = 32; o; o >>= 1) {
            s0 += __shfl_xor(s0, o); s1 += __shfl_xor(s1, o);
            s2 += __shfl_xor(s2, o); s3 += __shfl_xor(s3, o);
            d0 += __shfl_xor(d0, o); d1 += __shfl_xor(d1, o);
            d2 += __shfl_xor(d2, o); d3 += __shfl_xor(d3, o);
        }
        if (lane == 0) {
            float4* ap = (float4*)(att + (size_t)i * 8);
            ap[0] = make_float4(s0, s1, s2, s3);
            ap[1] = make_float4(d0, d1, d2, d3);
        }
    }
}

// ---------------- GAT aggregate: plain-exp softmax, 2-way MLP unroll ----------------
__global__ void __launch_bounds__(256) k_gat2(const unsigned short* __restrict__ h2b,
                                              const float* __restrict__ att,
                                              const int* __restrict__ rowptr,
                                              const int* __restrict__ col,
                                              unsigned short* __restrict__ oagg) {
    int tid = threadIdx.x;
    int lane = tid & 63;
    int gw = (blockIdx.x << 2) + (tid >> 6);
    int stride = gridDim.x << 2;
    for (int i = gw; i < N_NODES; i += stride) {
        int b = rowptr[i], e = rowptr[i + 1];
        float4 ai = *(const float4*)(att + (size_t)i * 8);
        float4 ad = *(const float4*)(att + (size_t)i * 8 + 4);
        float hv = b2f(h2b[(size_t)i * 64 + lane]);
        float w0 = __expf(lrelu(ai.x + ad.x));
        float w1 = __expf(lrelu(ai.y + ad.y));
        float w2 = __expf(lrelu(ai.z + ad.z));
        float w3 = __expf(lrelu(ai.w + ad.w));
        float s0 = w0, s1 = w1, s2 = w2, s3 = w3;
        float a0 = w0 * hv, a1 = w1 * hv, a2 = w2 * hv, a3 = w3 * hv;
        int p = b;
        for (; p + 2 <= e; p += 2) {
            int j0 = col[p], j1 = col[p + 1];
            float4 aj0 = *(const float4*)(att + (size_t)j0 * 8);
            float4 aj1 = *(const float4*)(att + (size_t)j1 * 8);
            float hj0 = b2f(h2b[(size_t)j0 * 64 + lane]);
            float hj1 = b2f(h2b[(size_t)j1 * 64 + lane]);
            float e00 = __expf(lrelu(aj0.x + ad.x));
            float e01 = __expf(lrelu(aj0.y + ad.y));
            float e02 = __expf(lrelu(aj0.z + ad.z));
            float e03 = __expf(lrelu(aj0.w + ad.w));
            float e10 = __expf(lrelu(aj1.x + ad.x));
            float e11 = __expf(lrelu(aj1.y + ad.y));
            float e12 = __expf(lrelu(aj1.z + ad.z));
            float e13 = __expf(lrelu(aj1.w + ad.w));
            s0 += e00 + e10; a0 = fmaf(e00, hj0, fmaf(e10, hj1, a0));
            s1 += e01 + e11; a1 = fmaf(e01, hj0, fmaf(e11, hj1, a1));
            s2 += e02 + e12; a2 = fmaf(e02, hj0, fmaf(e12, hj1, a2));
            s3 += e03 + e13; a3 = fmaf(e03, hj0, fmaf(e13, hj1, a3));
        }
        if (p < e) {
            int j = col[p];
            float4 aj = *(const float4*)(att + (size_t)j * 8);
            float hj = b2f(h2b[(size_t)j * 64 + lane]);
            float e0 = __expf(lrelu(aj.x + ad.x));
            float e1 = __expf(lrelu(aj.y + ad.y));
            float e2 = __expf(lrelu(aj.z + ad.z));
            float e3 = __expf(lrelu(aj.w + ad.w));
            s0 += e0; a0 = fmaf(e0, hj, a0);
            s1 += e1; a1 = fmaf(e1, hj, a1);
            s2 += e2; a2 = fmaf(e2, hj, a2);
            s3 += e3; a3 = fmaf(e3, hj, a3);
        }
        unsigned short* op = oagg + (size_t)i * 256 + lane;
        op[0]   = f2b(a0 / s0);
        op[64]  = f2b(a1 / s1);
        op[128] = f2b(a2 / s2);
        op[192] = f2b(a3 / s3);
    }
}

// ---------------- launch ----------------
extern "C" void kernel_launch(void* const* d_in, const int* in_sizes, int n_in,
                              void* d_out, int out_size, void* d_ws, size_t ws_size,
                              hipStream_t stream) {
    const float* x       = (const float*)d_in[0];
    const int*   ei      = (const int*)d_in[1];
    const float* W1l     = (const float*)d_in[2];
    const float* b1l     = (const float*)d_in[3];
    const float* W1r     = (const float*)d_in[4];
    const float* W2l     = (const float*)d_in[5];
    const float* b2l     = (const float*)d_in[6];
    const float* W2r     = (const float*)d_in[7];
    const float* g1      = (const float*)d_in[8];
    const float* be1     = (const float*)d_in[9];
    const float* g2      = (const float*)d_in[10];
    const float* be2     = (const float*)d_in[11];
    const float* Wg      = (const float*)d_in[12];
    const float* att_src = (const float*)d_in[13];
    const float* att_dst = (const float*)d_in[14];
    const float* bg      = (const float*)d_in[15];
    float* out = (float*)d_out;

    char* p = (char*)d_ws;
    auto alloc = [&](size_t bytes) -> char* {
        char* q = p;
        p += (bytes + 255) & ~(size_t)255;
        return q;
    };
    int*   cnt    = (int*)alloc((size_t)N_NODES * 4);
    float* stats  = (float*)alloc(1856 * 4);
    int*   rowptr = (int*)alloc((size_t)(N_NODES + 1) * 4);
    int*   bsums  = (int*)alloc(256 * 4);
    int*   col    = (int*)alloc((size_t)N_EDGES * 4);
    unsigned short* xb    = (unsigned short*)alloc((size_t)N_NODES * 128 * 2);  // 7.68MB
    unsigned short* agg1b = (unsigned short*)alloc((size_t)N_NODES * 128 * 2);  // 7.68MB, contiguous after xb
    unsigned short* h1b = (unsigned short*)alloc((size_t)N_NODES * 256 * 2);    // 15.36MB
    float* h2   = (float*)alloc((size_t)N_NODES * 64 * 4);                      // 7.68MB
    unsigned short* h2b = (unsigned short*)alloc((size_t)N_NODES * 64 * 2);     // 3.84MB
    float* att  = (float*)alloc((size_t)N_NODES * 8 * 4);
    unsigned short* w1lt = (unsigned short*)alloc(128 * 256 * 2);
    unsigned short* w1rt = (unsigned short*)alloc(128 * 256 * 2);
    unsigned short* w2lt = (unsigned short*)alloc(256 * 64 * 2);   // [w2lt|w2rt] contiguous [128][256]
    unsigned short* w2rt = (unsigned short*)alloc(256 * 64 * 2);
    unsigned short* btf  = (unsigned short*)alloc(64 * 256 * 2);

    // aliases (lifetimes): z2/r2 live in agg1b (dead after mgemm1, dead again before k_gat2);
    // oagg spans xb+agg1b (both dead by k_gat2)
    unsigned short* z2 = agg1b;                       // 3.84MB — L2-resident gather target
    unsigned short* r2 = agg1b + (size_t)N_NODES * 64;
    unsigned short* oagg = xb;

    float* sum1 = stats;        float* sq1 = stats + 256;
    float* A1s  = stats + 512;  float* B1s = stats + 768;
    float* sum2 = stats + 1024; float* sq2 = stats + 1088;
    float* A2s  = stats + 1152; float* B2s = stats + 1216;
    float* vsrc = stats + 1344; float* vdst = stats + 1600;

    const int* srcA = ei;
    const int* dstA = ei + N_EDGES;

    // prep (zero cnt/stats/out, cvt x, cvt+transpose weights, attention vecs)
    k_prep<<<1567, 256, 0, stream>>>(cnt, stats, out, x, xb, W1l, W1r, W2l, W2r, Wg,
                                     w1lt, w1rt, w2lt, w2rt, btf, att_src, att_dst, vsrc, vdst);
    // CSR build
    k_count<<<1172, 256, 0, stream>>>(dstA, cnt);
    k_scan1<<<118, 256, 0, stream>>>(cnt, rowptr, bsums);
    k_scan2<<<1, 128, 0, stream>>>(bsums, 118);
    k_scan3<<<118, 256, 0, stream>>>(rowptr, bsums, cnt);
    k_fill<<<1172, 256, 0, stream>>>(srcA, dstA, rowptr, cnt, col);

    // SAGE layer 1: aggregate -> dual GEMM (bf16 out + fused column stats) -> BN coeffs
    k_sage_agg_b<<<7500, 256, 0, stream>>>(xb, rowptr, col, agg1b);
    k_mgemm<true, false, true><<<dim3(469, 4), 256, 0, stream>>>(
        agg1b, w1lt, 128, xb, w1rt, 128, b1l, h1b, nullptr, N_NODES, 256, nullptr, nullptr, sum1, sq1);
    k_finstats<256><<<1, 256, 0, stream>>>(sum1, sq1, g1, be1, A1s, B1s);

    // SAGE layer 2: GEMM (fused BN+relu on A, split z2/r2 out) -> gather-add (fused stats) -> BN coeffs
    k_mgemm<true, true, false><<<dim3(469, 2), 256, 0, stream>>>(
        h1b, w2lt, 256, nullptr, nullptr, 0, nullptr, z2, r2, N_NODES, 128, A1s, B1s, nullptr, nullptr);
    k_sage_add<<<1875, 256, 0, stream>>>(z2, r2, rowptr, col, b2l, h2, sum2, sq2);
    k_finstats<64><<<1, 64, 0, stream>>>(sum2, sq2, g2, be2, A2s, B2s);

    // GAT: BN+relu+logits fused -> plain-exp softmax aggregate -> projection+mean GEMM into out
    k_attn2<<<1875, 256, 0, stream>>>(h2, A2s, B2s, vsrc, vdst, h2b, att);
    k_gat2<<<2048, 256, 0, stream>>>(h2b, att, rowptr, col, oagg);
    k_mgemm_mean<<<469, 256, 0, stream>>>(oagg, btf, bg, out, N_NODES);
}